// Round 5
// baseline (7941.095 us; speedup 1.0000x reference)
//
#include <hip/hip_runtime.h>

#define Cn 16
#define Dn 96
#define Sn (Dn*Dn*Dn)        /* 884736 */
#define DSTRIDE (Dn*Dn)      /* 9216 */
#define ENC_NEG_INF 0x007FFFFFu

typedef float v2f __attribute__((ext_vector_type(2)));
typedef float v4f __attribute__((ext_vector_type(4)));
typedef _Float16 v4h __attribute__((ext_vector_type(4)));

__device__ __forceinline__ v2f ld2(const float* p){
    v2f r; __builtin_memcpy(&r, p, 8); return r;
}
// monotonic float<->uint map for atomicMax on signed floats
__device__ __forceinline__ unsigned encf(float f){
    unsigned u = __float_as_uint(f);
    return (u & 0x80000000u) ? ~u : (u | 0x80000000u);
}
__device__ __forceinline__ float decf(unsigned u){
    return (u & 0x80000000u) ? __uint_as_float(u ^ 0x80000000u) : __uint_as_float(~u);
}
// tanh(x) = 1 - 2/(exp(2x)+1)
__device__ __forceinline__ float ftanh(float x){
    float t = __expf(2.0f*x);
    return 1.0f - __fdividef(2.0f, t + 1.0f);
}
__device__ __forceinline__ int clampi(int v){ return v<0?0:(v>Dn-1?Dn-1:v); }

__global__ void init_kernel(unsigned* __restrict__ maxv){
    if (threadIdx.x < 16) maxv[threadIdx.x] = ENC_NEG_INF;
}

// Stencil weight reorder (once):
//  wpW[(t*3+q)*16+c] = wp[(3c+q)*27+t]  (lane loads dwordx4 at c=4lg)
//  bpP[q*16+c] = bp[3c+q]
__global__ void tr_kernel(const float* __restrict__ wp, const float* __restrict__ bp,
                          float* __restrict__ wpW, float* __restrict__ bpP){
    const int i = blockIdx.x*256 + threadIdx.x;
    if (i < 1296){ const int c=i&15, tq=i>>4, q=tq%3, t=tq/3; wpW[i] = wp[(3*c+q)*27 + t]; }
    if (i < 48)  { const int q=i>>4, c=i&15; bpP[i] = bp[3*c + q]; }
}

// Pack MLP weights as MFMA *A*-fragments (M=out-feature, K=in-feature),
// split hi/lo f16 (3-term split-f16 GEMM ~ fp32 accuracy).
// A-frag tile (mt,ks): lane l elem e holds A[m=16mt+(l&15)][k=16ks+4*(l>>4)+e].
// Layer-1 k runs over the PERMUTED dwconv index j=q*16+c (orig = 3c+q), q=ks.
__global__ void pack_kernel(const float* __restrict__ w1, const float* __restrict__ w2,
                            const float* __restrict__ w3,
                            _Float16* __restrict__ w1Ah, _Float16* __restrict__ w1Al,
                            _Float16* __restrict__ w2Ah, _Float16* __restrict__ w2Al,
                            _Float16* __restrict__ w3Ah, _Float16* __restrict__ w3Al){
    const int i = blockIdx.x*256 + threadIdx.x;
    const int e = i & 3, l = (i>>2) & 63, tile = i >> 8;
    const int lr = l & 15, lg = l >> 4;
    if (i < 3072){ // w1 [64 out x 48 in], tiles = mt*3+ks
        const int ks = tile % 3, mt = tile / 3;
        const int c = 4*lg + e;                       // k = 16ks + 4lg + e -> q=ks, c
        const float v = w1[(16*mt + lr)*48 + 3*c + ks];
        const _Float16 hh = (_Float16)v;
        w1Ah[i] = hh; w1Al[i] = (_Float16)(v - (float)hh);
    }
    if (i < 4096){ // w2 [64 x 64], tiles = mt*4+ks
        const int ks = tile & 3, mt = tile >> 2;
        const float v = w2[(16*mt + lr)*64 + 16*ks + 4*lg + e];
        const _Float16 hh = (_Float16)v;
        w2Ah[i] = hh; w2Al[i] = (_Float16)(v - (float)hh);
    }
    if (i < 1024){ // w3 [16 x 64], tiles = ks
        const int ks = tile;
        const float v = w3[lr*64 + 16*ks + 4*lg + e];
        const _Float16 hh = (_Float16)v;
        w3Ah[i] = hh; w3Al[i] = (_Float16)(v - (float)hh);
    }
}

// global max of x0 ch3 -> slot; initial mask (u8) all-ones
__global__ __launch_bounds__(256) void prep_kernel(const float* __restrict__ x3,
    unsigned char* __restrict__ maskA, unsigned* __restrict__ slot)
{
    const int idx = blockIdx.x*256 + threadIdx.x;
    maskA[idx] = 1;
    float v = x3[idx];
    #pragma unroll
    for (int o=32;o;o>>=1) v = fmaxf(v, __shfl_down(v, o));
    __shared__ float red[4];
    const int lane = threadIdx.x & 63, wid = threadIdx.x >> 6;
    if (lane==0) red[wid]=v;
    __syncthreads();
    if (threadIdx.x==0){
        float m = fmaxf(fmaxf(red[0],red[1]), fmaxf(red[2],red[3]));
        atomicMax(slot, encf(m));
    }
}

// fused: masked stencil dwconv -> MLP 48->64->64->16, ALL fragments born in
// registers (voxels = N dim, weights = A operand): C-frag[m=4lg+r][n=lr] feeds
// next B-frag[k=4lg+e][n=lr] directly. ZERO LDS, zero barriers.
// CHANNEL-MAJOR global memory: per (tap,j,r) a scalar load with lane address
// (4lg+r)*Sn + vox(lr) -> each 16-lane group = one contiguous 64B segment
// (4 segments per instruction, 100% line utilization). Stores identical.
// Two row-passes (2 voxel-groups each) keep peak VGPR moderate.
__global__ __launch_bounds__(256, 4) void update_kernel(
    const float* __restrict__ xin, const unsigned char* __restrict__ min_,
    float* __restrict__ xout,
    const float* __restrict__ wpW, const float* __restrict__ bpP,
    const _Float16* __restrict__ w1Ah, const _Float16* __restrict__ w1Al,
    const float* __restrict__ b1,
    const _Float16* __restrict__ w2Ah, const _Float16* __restrict__ w2Al,
    const float* __restrict__ b2,
    const _Float16* __restrict__ w3Ah, const _Float16* __restrict__ w3Al,
    const float* __restrict__ b3,
    unsigned* __restrict__ slot_post)
{
    const int tid  = threadIdx.x;
    const int lane = tid & 63, wv = tid >> 6;
    const int lr   = lane & 15, lg = lane >> 4;
    const int wbase = blockIdx.x*32;
    const int d = blockIdx.z;
    const int w0 = wbase + lr;
    const float* xch = xin + (size_t)(4*lg)*Sn;   // this lane's channel base
    float vmax = -INFINITY;

    #pragma unroll 1
    for (int pass=0; pass<2; ++pass){
        const int h = blockIdx.y*8 + 2*wv + pass;

        // ---------------- stencil dwconv (fp32 VALU) -----------------------
        v2f pacc[2][3][2];
        #pragma unroll
        for (int j=0;j<2;++j)
            #pragma unroll
            for (int q=0;q<3;++q)
                #pragma unroll
                for (int pr=0;pr<2;++pr)
                    pacc[j][q][pr] = ld2(bpP + q*16 + 4*lg + 2*pr);

        #pragma unroll 1
        for (int dz=-1; dz<=1; ++dz){
            const int zz = d+dz, zc = clampi(zz);
            const int vz = (zz==zc);
            #pragma unroll
            for (int dy=-1; dy<=1; ++dy){
                const int yy = h+dy, yc = clampi(yy);
                const int vzy = vz & (yy==yc);
                const int rbase = zc*DSTRIDE + yc*Dn;
                #pragma unroll
                for (int dx=-1; dx<=1; ++dx){
                    const int t = (dz+1)*9 + (dy+1)*3 + (dx+1);
                    v4f wq[3];
                    #pragma unroll
                    for (int q=0;q<3;++q)
                        __builtin_memcpy(&wq[q], wpW + (t*3+q)*16 + 4*lg, 16);
                    #pragma unroll
                    for (int j=0;j<2;++j){
                        const int xx = w0 + 16*j + dx;
                        const int xc = clampi(xx);
                        const int noff = rbase + xc;
                        const float m = (vzy & (xx==xc)) ? (float)min_[noff] : 0.0f;
                        const float* xb = xch + noff;
                        v4f xv;
                        xv[0] = xb[0];
                        xv[1] = xb[(size_t)Sn];
                        xv[2] = xb[(size_t)2*Sn];
                        xv[3] = xb[(size_t)3*Sn];
                        const v2f m2 = {m, m};
                        const v2f x0m = (v2f){xv[0], xv[1]} * m2;
                        const v2f x1m = (v2f){xv[2], xv[3]} * m2;
                        #pragma unroll
                        for (int q=0;q<3;++q){
                            pacc[j][q][0] = __builtin_elementwise_fma((v2f){wq[q][0],wq[q][1]}, x0m, pacc[j][q][0]);
                            pacc[j][q][1] = __builtin_elementwise_fma((v2f){wq[q][2],wq[q][3]}, x1m, pacc[j][q][1]);
                        }
                    }
                }
            }
        }

        // center x + mask for residual
        const int idx0 = d*DSTRIDE + h*Dn + w0;
        v4f ctr[2]; float mctr[2];
        #pragma unroll
        for (int j=0;j<2;++j){
            const float* xb = xch + (idx0 + 16*j);
            ctr[j][0] = xb[0];
            ctr[j][1] = xb[(size_t)Sn];
            ctr[j][2] = xb[(size_t)2*Sn];
            ctr[j][3] = xb[(size_t)3*Sn];
            mctr[j] = (float)min_[idx0+16*j];
        }

        // -------- B1 frags (split hi/lo) from dwconv accumulators ----------
        v4h b1h[2][3], b1l[2][3];
        #pragma unroll
        for (int j=0;j<2;++j)
            #pragma unroll
            for (int q=0;q<3;++q){
                const float f0=pacc[j][q][0].x, f1=pacc[j][q][0].y;
                const float f2=pacc[j][q][1].x, f3v=pacc[j][q][1].y;
                v4h hi = {(_Float16)f0,(_Float16)f1,(_Float16)f2,(_Float16)f3v};
                v4h lo = {(_Float16)(f0-(float)hi[0]), (_Float16)(f1-(float)hi[1]),
                          (_Float16)(f2-(float)hi[2]), (_Float16)(f3v-(float)hi[3])};
                b1h[j][q]=hi; b1l[j][q]=lo;
            }

        // -------- GEMM1: c1[mt][j] = W1 @ p + b1 ---------------------------
        v4f c1[4][2];
        #pragma unroll
        for (int mt=0;mt<4;++mt){
            v4f bb; __builtin_memcpy(&bb, b1 + 16*mt + 4*lg, 16);
            c1[mt][0]=bb; c1[mt][1]=bb;
        }
        #pragma unroll
        for (int ks=0;ks<3;++ks)
            #pragma unroll
            for (int mt=0;mt<4;++mt){
                v4h ah, al;
                __builtin_memcpy(&ah, w1Ah + ((mt*3+ks)*64 + lane)*4, 8);
                __builtin_memcpy(&al, w1Al + ((mt*3+ks)*64 + lane)*4, 8);
                #pragma unroll
                for (int j=0;j<2;++j){
                    c1[mt][j] = __builtin_amdgcn_mfma_f32_16x16x16f16(ah, b1h[j][ks], c1[mt][j],0,0,0);
                    c1[mt][j] = __builtin_amdgcn_mfma_f32_16x16x16f16(al, b1h[j][ks], c1[mt][j],0,0,0);
                    c1[mt][j] = __builtin_amdgcn_mfma_f32_16x16x16f16(ah, b1l[j][ks], c1[mt][j],0,0,0);
                }
            }

        // -------- GEMM2: c2[mt][j] = W2 @ tanh(c1) + b2 --------------------
        v4f c2[4][2];
        #pragma unroll
        for (int mt=0;mt<4;++mt){
            v4f bb; __builtin_memcpy(&bb, b2 + 16*mt + 4*lg, 16);
            c2[mt][0]=bb; c2[mt][1]=bb;
        }
        #pragma unroll
        for (int ks=0;ks<4;++ks){
            v4h b2h[2], b2l[2];
            #pragma unroll
            for (int j=0;j<2;++j){
                float t0=ftanh(c1[ks][j][0]), t1=ftanh(c1[ks][j][1]);
                float t2=ftanh(c1[ks][j][2]), t3=ftanh(c1[ks][j][3]);
                v4h hi = {(_Float16)t0,(_Float16)t1,(_Float16)t2,(_Float16)t3};
                v4h lo = {(_Float16)(t0-(float)hi[0]), (_Float16)(t1-(float)hi[1]),
                          (_Float16)(t2-(float)hi[2]), (_Float16)(t3-(float)hi[3])};
                b2h[j]=hi; b2l[j]=lo;
            }
            #pragma unroll
            for (int mt=0;mt<4;++mt){
                v4h ah, al;
                __builtin_memcpy(&ah, w2Ah + ((mt*4+ks)*64 + lane)*4, 8);
                __builtin_memcpy(&al, w2Al + ((mt*4+ks)*64 + lane)*4, 8);
                #pragma unroll
                for (int j=0;j<2;++j){
                    c2[mt][j] = __builtin_amdgcn_mfma_f32_16x16x16f16(ah, b2h[j], c2[mt][j],0,0,0);
                    c2[mt][j] = __builtin_amdgcn_mfma_f32_16x16x16f16(al, b2h[j], c2[mt][j],0,0,0);
                    c2[mt][j] = __builtin_amdgcn_mfma_f32_16x16x16f16(ah, b2l[j], c2[mt][j],0,0,0);
                }
            }
        }

        // -------- GEMM3: c3[j] = W3 @ tanh(c2) + b3 ------------------------
        v4f c3[2];
        {
            v4f bb; __builtin_memcpy(&bb, b3 + 4*lg, 16);
            c3[0]=bb; c3[1]=bb;
        }
        #pragma unroll
        for (int ks=0;ks<4;++ks){
            v4h b3h[2], b3l[2];
            #pragma unroll
            for (int j=0;j<2;++j){
                float t0=ftanh(c2[ks][j][0]), t1=ftanh(c2[ks][j][1]);
                float t2=ftanh(c2[ks][j][2]), t3=ftanh(c2[ks][j][3]);
                v4h hi = {(_Float16)t0,(_Float16)t1,(_Float16)t2,(_Float16)t3};
                v4h lo = {(_Float16)(t0-(float)hi[0]), (_Float16)(t1-(float)hi[1]),
                          (_Float16)(t2-(float)hi[2]), (_Float16)(t3-(float)hi[3])};
                b3h[j]=hi; b3l[j]=lo;
            }
            v4h ah, al;
            __builtin_memcpy(&ah, w3Ah + (ks*64 + lane)*4, 8);
            __builtin_memcpy(&al, w3Al + (ks*64 + lane)*4, 8);
            #pragma unroll
            for (int j=0;j<2;++j){
                c3[j] = __builtin_amdgcn_mfma_f32_16x16x16f16(ah, b3h[j], c3[j],0,0,0);
                c3[j] = __builtin_amdgcn_mfma_f32_16x16x16f16(al, b3h[j], c3[j],0,0,0);
                c3[j] = __builtin_amdgcn_mfma_f32_16x16x16f16(ah, b3l[j], c3[j],0,0,0);
            }
        }

        // -------- residual + channel-major store (+ ch3 max) ---------------
        #pragma unroll
        for (int j=0;j<2;++j){
            const int vox = idx0 + 16*j;
            v4f xn;
            #pragma unroll
            for (int r=0;r<4;++r) xn[r] = fmaf(ctr[j][r], mctr[j], c3[j][r]);
            float* ob = xout + (size_t)(4*lg)*Sn + vox;
            ob[0] = xn[0];
            ob[(size_t)Sn] = xn[1];
            ob[(size_t)2*Sn] = xn[2];
            ob[(size_t)3*Sn] = xn[3];
            if (lg==0) vmax = fmaxf(vmax, xn[3]);
        }
    }

    #pragma unroll
    for (int o=32;o;o>>=1) vmax = fmaxf(vmax, __shfl_down(vmax, o));
    if (lane==0) atomicMax(slot_post, encf(vmax));
}

// alive0 from masked old ch3 plane, alive1 from unmasked new ch3 plane
// (both contiguous, channel-major); life includes boundary zero
// x[:, :, -1, 48:, :]=0; also produces next step's pre-max.
__global__ __launch_bounds__(256) void mask_kernel(
    const float* __restrict__ x3old, const unsigned char* __restrict__ min_,
    const float* __restrict__ x3new, unsigned char* __restrict__ mout,
    const unsigned* __restrict__ slot_pre, const unsigned* __restrict__ slot_post,
    unsigned* __restrict__ slot_next)
{
    const int idx = blockIdx.x*256 + threadIdx.x;
    const int w = idx % Dn;
    const int h = (idx / Dn) % Dn;
    const int d = idx / DSTRIDE;
    const float th0 = 0.1f * decf(*slot_pre);
    const float th1 = 0.1f * decf(*slot_post);
    float a0 = -INFINITY, a1 = -INFINITY;
    #pragma unroll
    for (int t=0;t<27;++t){
        const int dz=t/9-1, dy=(t/3)%3-1, dx=t%3-1;
        const int zz=d+dz, yy=h+dy, xx=w+dx;
        if ((unsigned)zz<(unsigned)Dn && (unsigned)yy<(unsigned)Dn &&
            (unsigned)xx<(unsigned)Dn){
            const int noff = idx + dz*DSTRIDE + dy*Dn + dx;
            a0 = fmaxf(a0, x3old[noff] * (float)min_[noff]);
            a1 = fmaxf(a1, x3new[noff]);
        }
    }
    const bool life = (a0 > th0) && (a1 > th1) && !(d==Dn-1 && h>=48);
    mout[idx] = life ? 1 : 0;
    const float mv = life ? 1.0f : 0.0f;

    float f3 = x3new[idx]*mv;   // final ch3 value -> pre-max of next step
    #pragma unroll
    for (int o=32;o;o>>=1) f3 = fmaxf(f3, __shfl_down(f3, o));
    __shared__ float red[4];
    const int lane = threadIdx.x & 63, wid = threadIdx.x >> 6;
    if (lane==0) red[wid]=f3;
    __syncthreads();
    if (threadIdx.x==0){
        float m = fmaxf(fmaxf(red[0],red[1]), fmaxf(red[2],red[3]));
        atomicMax(slot_next, encf(m));
    }
}

// final: apply last step's mask in place on d_out (channel-major)
__global__ __launch_bounds__(256) void apply_kernel(float* __restrict__ x,
    const unsigned char* __restrict__ mk)
{
    const int idx = blockIdx.x*256 + threadIdx.x;
    const float m = (float)mk[idx];
    #pragma unroll
    for (int c=0;c<Cn;++c) x[(size_t)c*Sn+idx] *= m;
}

extern "C" void kernel_launch(void* const* d_in, const int* in_sizes, int n_in,
                              void* d_out, int out_size, void* d_ws, size_t ws_size,
                              hipStream_t stream)
{
    const float* x0 = (const float*)d_in[0];
    const float* wp = (const float*)d_in[1];
    const float* bp = (const float*)d_in[2];
    const float* w1 = (const float*)d_in[3];
    const float* b1 = (const float*)d_in[4];
    const float* w2 = (const float*)d_in[5];
    const float* b2 = (const float*)d_in[6];
    const float* w3 = (const float*)d_in[7];
    const float* b3 = (const float*)d_in[8];
    float* out = (float*)d_out;

    // ws: T0 16*Sn f32 | maskA,maskB u8 Sn each | maxv | wpW 1296 f | bpP 48 f |
    //     A-frag packs 16384 h (32 KB)
    float* T0 = (float*)d_ws;
    unsigned char* mA = (unsigned char*)(T0 + (size_t)Cn*Sn);
    unsigned char* mB = mA + Sn;
    unsigned* maxv = (unsigned*)(mB + Sn);
    float* wpW = (float*)(maxv + 16);
    float* bpP = wpW + 1296;
    _Float16* w1Ah = (_Float16*)(bpP + 48);
    _Float16* w1Al = w1Ah + 3072;
    _Float16* w2Ah = w1Al + 3072;
    _Float16* w2Al = w2Ah + 4096;
    _Float16* w3Ah = w2Al + 4096;
    _Float16* w3Al = w3Ah + 1024;

    init_kernel<<<1, 64, 0, stream>>>(maxv);
    tr_kernel<<<6, 256, 0, stream>>>(wp, bp, wpW, bpP);
    pack_kernel<<<16, 256, 0, stream>>>(w1, w2, w3, w1Ah, w1Al, w2Ah, w2Al, w3Ah, w3Al);
    prep_kernel<<<Sn/256, 256, 0, stream>>>(x0 + (size_t)3*Sn, mA, &maxv[0]);

    // all states channel-major; ping-pong T0(ws) <-> d_out; step 3 ends in d_out
    const float* xi[4] = {x0, T0, out, T0};
    float*       xo[4] = {T0, out, T0, out};
    const unsigned char* mi[4] = {mA, mB, mA, mB};
    unsigned char*       mo[4] = {mB, mA, mB, mA};

    dim3 ugrid(Dn/32, Dn/8, Dn);
    for (int s=0; s<4; ++s){
        update_kernel<<<ugrid, 256, 0, stream>>>(xi[s], mi[s], xo[s],
            wpW, bpP, w1Ah, w1Al, b1, w2Ah, w2Al, b2, w3Ah, w3Al, b3, &maxv[2*s+1]);
        mask_kernel<<<Sn/256, 256, 0, stream>>>(xi[s] + (size_t)3*Sn, mi[s],
            xo[s] + (size_t)3*Sn, mo[s], &maxv[2*s], &maxv[2*s+1], &maxv[2*s+2]);
    }
    apply_kernel<<<Sn/256, 256, 0, stream>>>(out, mA);
}

// Round 7
// 1637.336 us; speedup vs baseline: 4.8500x; 4.8500x over previous
//
#include <hip/hip_runtime.h>

#define Cn 16
#define Dn 96
#define Sn (Dn*Dn*Dn)        /* 884736 */
#define DSTRIDE (Dn*Dn)      /* 9216 */
#define ENC_NEG_INF 0x007FFFFFu
#define PSTR 49              /* LDS row stride in f32: 49*4B, 49%32 odd -> bank-rotating */

typedef float v2f __attribute__((ext_vector_type(2)));
typedef float v4f __attribute__((ext_vector_type(4)));
typedef _Float16 v4h __attribute__((ext_vector_type(4)));

__device__ __forceinline__ v2f ld2(const float* p){
    v2f r; __builtin_memcpy(&r, p, 8); return r;
}
// monotonic float<->uint map for atomicMax on signed floats
__device__ __forceinline__ unsigned encf(float f){
    unsigned u = __float_as_uint(f);
    return (u & 0x80000000u) ? ~u : (u | 0x80000000u);
}
__device__ __forceinline__ float decf(unsigned u){
    return (u & 0x80000000u) ? __uint_as_float(u ^ 0x80000000u) : __uint_as_float(~u);
}
// tanh(x) = 1 - 2/(exp(2x)+1)
__device__ __forceinline__ float ftanh(float x){
    float t = __expf(2.0f*x);
    return 1.0f - __fdividef(2.0f, t + 1.0f);
}
__device__ __forceinline__ int clampi(int v){ return v<0?0:(v>Dn-1?Dn-1:v); }

__global__ void init_kernel(unsigned* __restrict__ maxv){
    if (threadIdx.x < 16) maxv[threadIdx.x] = ENC_NEG_INF;
}

// Stencil weight reorder (once):
//  wpT[t*48+q*16+c]=wp[(3c+q)*27+t]; bpP[q*16+c]=bp[3c+q]
__global__ void tr_kernel(const float* __restrict__ wp, const float* __restrict__ bp,
                          float* __restrict__ wpT, float* __restrict__ bpP){
    const int i = blockIdx.x*256 + threadIdx.x;
    if (i < 1296){ const int t=i/48, r=i%48, q=r>>4, c=r&15; wpT[i] = wp[(3*c+q)*27 + t]; }
    if (i < 48)  { const int q=i>>4, c=i&15; bpP[i] = bp[3*c + q]; }
}

// Pack MLP weights as MFMA *A*-fragments (M=out-feature, K=in-feature),
// split hi/lo f16 (3-term split-f16 GEMM ~ fp32 accuracy).
// A-frag tile (mt,ks): lane l elem e holds A[m=16mt+(l&15)][k=16ks+4*(l>>4)+e].
// Layer-1 k runs over the PERMUTED dwconv index j=q*16+c (orig = 3c+q), q=ks.
// (verified correct in R4/R5 runs, absmax 0.03125)
__global__ void pack_kernel(const float* __restrict__ w1, const float* __restrict__ w2,
                            const float* __restrict__ w3,
                            _Float16* __restrict__ w1Ah, _Float16* __restrict__ w1Al,
                            _Float16* __restrict__ w2Ah, _Float16* __restrict__ w2Al,
                            _Float16* __restrict__ w3Ah, _Float16* __restrict__ w3Al){
    const int i = blockIdx.x*256 + threadIdx.x;
    const int e = i & 3, l = (i>>2) & 63, tile = i >> 8;
    const int lr = l & 15, lg = l >> 4;
    if (i < 3072){ // w1 [64 out x 48 in], tiles = mt*3+ks
        const int ks = tile % 3, mt = tile / 3;
        const int c = 4*lg + e;                       // k = 16ks + 4lg + e -> q=ks, c
        const float v = w1[(16*mt + lr)*48 + 3*c + ks];
        const _Float16 hh = (_Float16)v;
        w1Ah[i] = hh; w1Al[i] = (_Float16)(v - (float)hh);
    }
    if (i < 4096){ // w2 [64 x 64], tiles = mt*4+ks
        const int ks = tile & 3, mt = tile >> 2;
        const float v = w2[(16*mt + lr)*64 + 16*ks + 4*lg + e];
        const _Float16 hh = (_Float16)v;
        w2Ah[i] = hh; w2Al[i] = (_Float16)(v - (float)hh);
    }
    if (i < 1024){ // w3 [16 x 64], tiles = ks
        const int ks = tile;
        const float v = w3[lr*64 + 16*ks + 4*lg + e];
        const _Float16 hh = (_Float16)v;
        w3Ah[i] = hh; w3Al[i] = (_Float16)(v - (float)hh);
    }
}

// global max of x0 ch3 -> slot; initial mask (u8) all-ones
__global__ __launch_bounds__(256) void prep_kernel(const float* __restrict__ x3,
    unsigned char* __restrict__ maskA, unsigned* __restrict__ slot)
{
    const int idx = blockIdx.x*256 + threadIdx.x;
    maskA[idx] = 1;
    float v = x3[idx];
    #pragma unroll
    for (int o=32;o;o>>=1) v = fmaxf(v, __shfl_down(v, o));
    __shared__ float red[4];
    const int lane = threadIdx.x & 63, wid = threadIdx.x >> 6;
    if (lane==0) red[wid]=v;
    __syncthreads();
    if (threadIdx.x==0){
        float m = fmaxf(fmaxf(red[0],red[1]), fmaxf(red[2],red[3]));
        atomicMax(slot, encf(m));
    }
}

struct XBuf { float x[16]; float m; int v; };

__device__ __forceinline__ void prefetch_t(int t, int d, int h, int w,
    const float* __restrict__ xin, const unsigned char* __restrict__ min_, XBuf& B)
{
    const int zz = d + t/9 - 1;
    const int yy = h + (t/3)%3 - 1;
    const int xx = w + t%3 - 1;
    const int zc = clampi(zz), yc = clampi(yy), xc = clampi(xx);
    B.v = (zz==zc) & (yy==yc) & (xx==xc);
    const int noff = zc*DSTRIDE + yc*Dn + xc;
    B.m = (float)min_[noff];
    #pragma unroll
    for (int c=0;c<16;++c) B.x[c] = xin[(size_t)c*Sn + noff];
}

__device__ __forceinline__ void accum_t(int t, const XBuf& A,
    const float* __restrict__ wpT, v2f* pv)
{
    const float mv = A.v ? A.m : 0.0f;
    const v2f mvv = {mv, mv};
    const float* wrow = wpT + t*48;
    #pragma unroll
    for (int i=0;i<8;++i){
        v2f xv = {A.x[2*i], A.x[2*i+1]};
        v2f xm = xv * mvv;                               // v_pk_mul_f32
        pv[i]    = __builtin_elementwise_fma(ld2(wrow + 2*i),      xm, pv[i]);
        pv[8+i]  = __builtin_elementwise_fma(ld2(wrow + 16 + 2*i), xm, pv[8+i]);
        pv[16+i] = __builtin_elementwise_fma(ld2(wrow + 32 + 2*i), xm, pv[16+i]);
    }
}

// fused: masked stencil dwconv (R2 coalesced thread<->voxel mapping) ->
// ONE LDS bridge (p as f32, wave-private rows, stride 49 = bank-rotating) ->
// register-chained MLP 48->64->64->16 (weights-as-A; C-frag of each GEMM IS
// the next GEMM's B-frag, zero data movement) -> c3 back through same LDS
// rows (cols 0..15, p already consumed) -> R2 coalesced residual + store.
// ZERO barriers (all LDS rows wave-private). LDS 50176 B -> 3 blocks/CU.
__global__ __launch_bounds__(256, 3) void update_kernel(
    const float* __restrict__ xin, const unsigned char* __restrict__ min_,
    float* __restrict__ xout,
    const float* __restrict__ wpT, const float* __restrict__ bpP,
    const _Float16* __restrict__ w1Ah, const _Float16* __restrict__ w1Al,
    const float* __restrict__ b1,
    const _Float16* __restrict__ w2Ah, const _Float16* __restrict__ w2Al,
    const float* __restrict__ b2,
    const _Float16* __restrict__ w3Ah, const _Float16* __restrict__ w3Al,
    const float* __restrict__ b3,
    unsigned* __restrict__ slot_post)
{
    __shared__ float sP[256*PSTR];   // 50176 B

    const int tid = threadIdx.x;
    const int w = blockIdx.x*32 + (tid & 31);
    const int h = blockIdx.y*8  + (tid >> 5);
    const int d = blockIdx.z;
    const int idx = d*DSTRIDE + h*Dn + w;

    const int lane = tid & 63;
    const int wv   = tid >> 6;       // wave id 0..3
    const int lr   = lane & 15;
    const int lg   = lane >> 4;

    // ---------------- stencil dwconv (R2 fp32 path, coalesced) -------------
    v2f pv[24];
    #pragma unroll
    for (int j=0;j<24;++j) pv[j] = ld2(bpP + 2*j);

    XBuf A, B;
    prefetch_t(0, d, h, w, xin, min_, A);
    #pragma unroll 1
    for (int t=0; t<26; t+=2){
        prefetch_t(t+1, d, h, w, xin, min_, B);
        accum_t(t, A, wpT, pv);
        prefetch_t(t+2, d, h, w, xin, min_, A);
        accum_t(t+1, B, wpT, pv);
    }
    accum_t(26, A, wpT, pv);

    // p -> LDS row tid (f32, cols 0..47 in q*16+c order)
    {
        float* pr = sP + tid*PSTR;
        #pragma unroll
        for (int jj=0;jj<12;++jj){
            pr[4*jj+0] = pv[2*jj].x;  pr[4*jj+1] = pv[2*jj].y;
            pr[4*jj+2] = pv[2*jj+1].x; pr[4*jj+3] = pv[2*jj+1].y;
        }
    }

    // ---------------- register-chained MLP, two j-halves -------------------
    // wave rows: 64wv..64wv+63. group j=(r2,hw): row = 64wv+32*r2+16*hw+lr.
    // half 0 -> j in {(0,0),(0,1)} rows 0..31; half 1 -> rows 32..63.
    const int rowbase = 64*wv;
    #pragma unroll 1
    for (int half=0; half<2; ++half){
        const int r0 = rowbase + 32*half + lr;   // jj=0
        const int r1 = r0 + 16;                  // jj=1

        __builtin_amdgcn_s_setprio(1);
        // -------- GEMM1: c1 = W1 @ p + b1 ------------------------------
        v4f c1[4][2];
        #pragma unroll
        for (int mt=0;mt<4;++mt){
            v4f bb; __builtin_memcpy(&bb, b1 + 16*mt + 4*lg, 16);
            c1[mt][0]=bb; c1[mt][1]=bb;
        }
        #pragma unroll
        for (int ks=0;ks<3;++ks){
            v4h bh[2], bl[2];
            #pragma unroll
            for (int jj=0;jj<2;++jj){
                const float* pr = sP + (jj ? r1 : r0)*PSTR + 16*ks + 4*lg;
                v4f P = {pr[0], pr[1], pr[2], pr[3]};
                v4h hi = {(_Float16)P[0],(_Float16)P[1],(_Float16)P[2],(_Float16)P[3]};
                v4h lo = {(_Float16)(P[0]-(float)hi[0]), (_Float16)(P[1]-(float)hi[1]),
                          (_Float16)(P[2]-(float)hi[2]), (_Float16)(P[3]-(float)hi[3])};
                bh[jj]=hi; bl[jj]=lo;
            }
            #pragma unroll
            for (int mt=0;mt<4;++mt){
                v4h ah, al;
                __builtin_memcpy(&ah, w1Ah + ((mt*3+ks)*64 + lane)*4, 8);
                __builtin_memcpy(&al, w1Al + ((mt*3+ks)*64 + lane)*4, 8);
                #pragma unroll
                for (int jj=0;jj<2;++jj){
                    c1[mt][jj] = __builtin_amdgcn_mfma_f32_16x16x16f16(ah, bh[jj], c1[mt][jj],0,0,0);
                    c1[mt][jj] = __builtin_amdgcn_mfma_f32_16x16x16f16(al, bh[jj], c1[mt][jj],0,0,0);
                    c1[mt][jj] = __builtin_amdgcn_mfma_f32_16x16x16f16(ah, bl[jj], c1[mt][jj],0,0,0);
                }
            }
        }

        // -------- GEMM2: c2 = W2 @ tanh(c1) + b2 -----------------------
        v4f c2[4][2];
        #pragma unroll
        for (int mt=0;mt<4;++mt){
            v4f bb; __builtin_memcpy(&bb, b2 + 16*mt + 4*lg, 16);
            c2[mt][0]=bb; c2[mt][1]=bb;
        }
        #pragma unroll
        for (int ks=0;ks<4;++ks){
            v4h bh[2], bl[2];
            #pragma unroll
            for (int jj=0;jj<2;++jj){
                float t0=ftanh(c1[ks][jj][0]), t1=ftanh(c1[ks][jj][1]);
                float t2=ftanh(c1[ks][jj][2]), t3=ftanh(c1[ks][jj][3]);
                v4h hi = {(_Float16)t0,(_Float16)t1,(_Float16)t2,(_Float16)t3};
                v4h lo = {(_Float16)(t0-(float)hi[0]), (_Float16)(t1-(float)hi[1]),
                          (_Float16)(t2-(float)hi[2]), (_Float16)(t3-(float)hi[3])};
                bh[jj]=hi; bl[jj]=lo;
            }
            #pragma unroll
            for (int mt=0;mt<4;++mt){
                v4h ah, al;
                __builtin_memcpy(&ah, w2Ah + ((mt*4+ks)*64 + lane)*4, 8);
                __builtin_memcpy(&al, w2Al + ((mt*4+ks)*64 + lane)*4, 8);
                #pragma unroll
                for (int jj=0;jj<2;++jj){
                    c2[mt][jj] = __builtin_amdgcn_mfma_f32_16x16x16f16(ah, bh[jj], c2[mt][jj],0,0,0);
                    c2[mt][jj] = __builtin_amdgcn_mfma_f32_16x16x16f16(al, bh[jj], c2[mt][jj],0,0,0);
                    c2[mt][jj] = __builtin_amdgcn_mfma_f32_16x16x16f16(ah, bl[jj], c2[mt][jj],0,0,0);
                }
            }
        }

        // -------- GEMM3: c3 = W3 @ tanh(c2) + b3 -----------------------
        v4f c3[2];
        {
            v4f bb; __builtin_memcpy(&bb, b3 + 4*lg, 16);
            c3[0]=bb; c3[1]=bb;
        }
        #pragma unroll
        for (int ks=0;ks<4;++ks){
            v4h bh[2], bl[2];
            #pragma unroll
            for (int jj=0;jj<2;++jj){
                float t0=ftanh(c2[ks][jj][0]), t1=ftanh(c2[ks][jj][1]);
                float t2=ftanh(c2[ks][jj][2]), t3=ftanh(c2[ks][jj][3]);
                v4h hi = {(_Float16)t0,(_Float16)t1,(_Float16)t2,(_Float16)t3};
                v4h lo = {(_Float16)(t0-(float)hi[0]), (_Float16)(t1-(float)hi[1]),
                          (_Float16)(t2-(float)hi[2]), (_Float16)(t3-(float)hi[3])};
                bh[jj]=hi; bl[jj]=lo;
            }
            v4h ah, al;
            __builtin_memcpy(&ah, w3Ah + (ks*64 + lane)*4, 8);
            __builtin_memcpy(&al, w3Al + (ks*64 + lane)*4, 8);
            #pragma unroll
            for (int jj=0;jj<2;++jj){
                c3[jj] = __builtin_amdgcn_mfma_f32_16x16x16f16(ah, bh[jj], c3[jj],0,0,0);
                c3[jj] = __builtin_amdgcn_mfma_f32_16x16x16f16(al, bh[jj], c3[jj],0,0,0);
                c3[jj] = __builtin_amdgcn_mfma_f32_16x16x16f16(ah, bl[jj], c3[jj],0,0,0);
            }
        }
        __builtin_amdgcn_s_setprio(0);

        // c3 -> LDS cols 0..15 of rows r0/r1 (p there already consumed;
        // rows are wave-private -> no barrier)
        #pragma unroll
        for (int e=0;e<4;++e){
            sP[r0*PSTR + 4*lg + e] = c3[0][e];
            sP[r1*PSTR + 4*lg + e] = c3[1][e];
        }
    }

    // ---------------- residual + coalesced channel-major store -------------
    const float mcen = (float)min_[idx];
    const float* orow = sP + tid*PSTR;
    float v3 = 0.0f;
    #pragma unroll
    for (int c=0;c<16;++c){
        const float xn = fmaf(xin[(size_t)c*Sn+idx], mcen, orow[c]);
        xout[(size_t)c*Sn+idx] = xn;
        if (c==3) v3 = xn;
    }

    #pragma unroll
    for (int o=32;o;o>>=1) v3 = fmaxf(v3, __shfl_down(v3, o));
    if ((tid & 63) == 0) atomicMax(slot_post, encf(v3));
}

// alive0 from masked old ch3 plane, alive1 from unmasked new ch3 plane
// (both contiguous, channel-major); life includes boundary zero
// x[:, :, -1, 48:, :]=0; also produces next step's pre-max.
__global__ __launch_bounds__(256) void mask_kernel(
    const float* __restrict__ x3old, const unsigned char* __restrict__ min_,
    const float* __restrict__ x3new, unsigned char* __restrict__ mout,
    const unsigned* __restrict__ slot_pre, const unsigned* __restrict__ slot_post,
    unsigned* __restrict__ slot_next)
{
    const int idx = blockIdx.x*256 + threadIdx.x;
    const int w = idx % Dn;
    const int h = (idx / Dn) % Dn;
    const int d = idx / DSTRIDE;
    const float th0 = 0.1f * decf(*slot_pre);
    const float th1 = 0.1f * decf(*slot_post);
    float a0 = -INFINITY, a1 = -INFINITY;
    #pragma unroll
    for (int t=0;t<27;++t){
        const int dz=t/9-1, dy=(t/3)%3-1, dx=t%3-1;
        const int zz=d+dz, yy=h+dy, xx=w+dx;
        if ((unsigned)zz<(unsigned)Dn && (unsigned)yy<(unsigned)Dn &&
            (unsigned)xx<(unsigned)Dn){
            const int noff = idx + dz*DSTRIDE + dy*Dn + dx;
            a0 = fmaxf(a0, x3old[noff] * (float)min_[noff]);
            a1 = fmaxf(a1, x3new[noff]);
        }
    }
    const bool life = (a0 > th0) && (a1 > th1) && !(d==Dn-1 && h>=48);
    mout[idx] = life ? 1 : 0;
    const float mv = life ? 1.0f : 0.0f;

    float f3 = x3new[idx]*mv;   // final ch3 value -> pre-max of next step
    #pragma unroll
    for (int o=32;o;o>>=1) f3 = fmaxf(f3, __shfl_down(f3, o));
    __shared__ float red[4];
    const int lane = threadIdx.x & 63, wid = threadIdx.x >> 6;
    if (lane==0) red[wid]=f3;
    __syncthreads();
    if (threadIdx.x==0){
        float m = fmaxf(fmaxf(red[0],red[1]), fmaxf(red[2],red[3]));
        atomicMax(slot_next, encf(m));
    }
}

// final: apply last step's mask in place on d_out (channel-major)
__global__ __launch_bounds__(256) void apply_kernel(float* __restrict__ x,
    const unsigned char* __restrict__ mk)
{
    const int idx = blockIdx.x*256 + threadIdx.x;
    const float m = (float)mk[idx];
    #pragma unroll
    for (int c=0;c<Cn;++c) x[(size_t)c*Sn+idx] *= m;
}

extern "C" void kernel_launch(void* const* d_in, const int* in_sizes, int n_in,
                              void* d_out, int out_size, void* d_ws, size_t ws_size,
                              hipStream_t stream)
{
    const float* x0 = (const float*)d_in[0];
    const float* wp = (const float*)d_in[1];
    const float* bp = (const float*)d_in[2];
    const float* w1 = (const float*)d_in[3];
    const float* b1 = (const float*)d_in[4];
    const float* w2 = (const float*)d_in[5];
    const float* b2 = (const float*)d_in[6];
    const float* w3 = (const float*)d_in[7];
    const float* b3 = (const float*)d_in[8];
    float* out = (float*)d_out;

    // ws: T0 16*Sn f32 | maskA,maskB u8 Sn each | maxv | wpT 1296 f | bpP 48 f |
    //     A-frag packs 16384 h (32 KB)
    float* T0 = (float*)d_ws;
    unsigned char* mA = (unsigned char*)(T0 + (size_t)Cn*Sn);
    unsigned char* mB = mA + Sn;
    unsigned* maxv = (unsigned*)(mB + Sn);
    float* wpT = (float*)(maxv + 16);
    float* bpP = wpT + 1296;
    _Float16* w1Ah = (_Float16*)(bpP + 48);
    _Float16* w1Al = w1Ah + 3072;
    _Float16* w2Ah = w1Al + 3072;
    _Float16* w2Al = w2Ah + 4096;
    _Float16* w3Ah = w2Al + 4096;
    _Float16* w3Al = w3Ah + 1024;

    init_kernel<<<1, 64, 0, stream>>>(maxv);
    tr_kernel<<<6, 256, 0, stream>>>(wp, bp, wpT, bpP);
    pack_kernel<<<16, 256, 0, stream>>>(w1, w2, w3, w1Ah, w1Al, w2Ah, w2Al, w3Ah, w3Al);
    prep_kernel<<<Sn/256, 256, 0, stream>>>(x0 + (size_t)3*Sn, mA, &maxv[0]);

    // all states channel-major; ping-pong T0(ws) <-> d_out; step 3 ends in d_out
    const float* xi[4] = {x0, T0, out, T0};
    float*       xo[4] = {T0, out, T0, out};
    const unsigned char* mi[4] = {mA, mB, mA, mB};
    unsigned char*       mo[4] = {mB, mA, mB, mA};

    dim3 ugrid(Dn/32, Dn/8, Dn);
    for (int s=0; s<4; ++s){
        update_kernel<<<ugrid, 256, 0, stream>>>(xi[s], mi[s], xo[s],
            wpT, bpP, w1Ah, w1Al, b1, w2Ah, w2Al, b2, w3Ah, w3Al, b3, &maxv[2*s+1]);
        mask_kernel<<<Sn/256, 256, 0, stream>>>(xi[s] + (size_t)3*Sn, mi[s],
            xo[s] + (size_t)3*Sn, mo[s], &maxv[2*s], &maxv[2*s+1], &maxv[2*s+2]);
    }
    apply_kernel<<<Sn/256, 256, 0, stream>>>(out, mA);
}

// Round 8
// 1421.995 us; speedup vs baseline: 5.5845x; 1.1514x over previous
//
#include <hip/hip_runtime.h>

#define Cn 16
#define Dn 96
#define Sn (Dn*Dn*Dn)        /* 884736 */
#define DSTRIDE (Dn*Dn)      /* 9216 */
#define ENC_NEG_INF 0x007FFFFFu
#define PSTR 52              /* LDS row stride in f32: 208 B, 16B-aligned rows; 52%32=20 rotates bank start over 8-row groups */

typedef float v2f __attribute__((ext_vector_type(2)));
typedef float v4f __attribute__((ext_vector_type(4)));
typedef _Float16 v4h __attribute__((ext_vector_type(4)));

__device__ __forceinline__ v2f ld2(const float* p){
    v2f r; __builtin_memcpy(&r, p, 8); return r;
}
// monotonic float<->uint map for atomicMax on signed floats
__device__ __forceinline__ unsigned encf(float f){
    unsigned u = __float_as_uint(f);
    return (u & 0x80000000u) ? ~u : (u | 0x80000000u);
}
__device__ __forceinline__ float decf(unsigned u){
    return (u & 0x80000000u) ? __uint_as_float(u ^ 0x80000000u) : __uint_as_float(~u);
}
// tanh(x) = 1 - 2/(exp(2x)+1)
__device__ __forceinline__ float ftanh(float x){
    float t = __expf(2.0f*x);
    return 1.0f - __fdividef(2.0f, t + 1.0f);
}
__device__ __forceinline__ int clampi(int v){ return v<0?0:(v>Dn-1?Dn-1:v); }

__global__ void init_kernel(unsigned* __restrict__ maxv){
    if (threadIdx.x < 16) maxv[threadIdx.x] = ENC_NEG_INF;
}

// Stencil weight reorder (once):
//  wpT[t*48+q*16+c]=wp[(3c+q)*27+t]; bpP[q*16+c]=bp[3c+q]
__global__ void tr_kernel(const float* __restrict__ wp, const float* __restrict__ bp,
                          float* __restrict__ wpT, float* __restrict__ bpP){
    const int i = blockIdx.x*256 + threadIdx.x;
    if (i < 1296){ const int t=i/48, r=i%48, q=r>>4, c=r&15; wpT[i] = wp[(3*c+q)*27 + t]; }
    if (i < 48)  { const int q=i>>4, c=i&15; bpP[i] = bp[3*c + q]; }
}

// Pack MLP weights as MFMA *A*-fragments (M=out-feature, K=in-feature),
// split hi/lo f16 (3-term split-f16 GEMM ~ fp32 accuracy).
// A-frag tile (mt,ks): lane l elem e holds A[m=16mt+(l&15)][k=16ks+4*(l>>4)+e].
// Layer-1 k runs over the PERMUTED dwconv index j=q*16+c (orig = 3c+q), q=ks.
// (verified correct in R4/R5/R7 runs, absmax 0.03125)
__global__ void pack_kernel(const float* __restrict__ w1, const float* __restrict__ w2,
                            const float* __restrict__ w3,
                            _Float16* __restrict__ w1Ah, _Float16* __restrict__ w1Al,
                            _Float16* __restrict__ w2Ah, _Float16* __restrict__ w2Al,
                            _Float16* __restrict__ w3Ah, _Float16* __restrict__ w3Al){
    const int i = blockIdx.x*256 + threadIdx.x;
    const int e = i & 3, l = (i>>2) & 63, tile = i >> 8;
    const int lr = l & 15, lg = l >> 4;
    if (i < 3072){ // w1 [64 out x 48 in], tiles = mt*3+ks
        const int ks = tile % 3, mt = tile / 3;
        const int c = 4*lg + e;                       // k = 16ks + 4lg + e -> q=ks, c
        const float v = w1[(16*mt + lr)*48 + 3*c + ks];
        const _Float16 hh = (_Float16)v;
        w1Ah[i] = hh; w1Al[i] = (_Float16)(v - (float)hh);
    }
    if (i < 4096){ // w2 [64 x 64], tiles = mt*4+ks
        const int ks = tile & 3, mt = tile >> 2;
        const float v = w2[(16*mt + lr)*64 + 16*ks + 4*lg + e];
        const _Float16 hh = (_Float16)v;
        w2Ah[i] = hh; w2Al[i] = (_Float16)(v - (float)hh);
    }
    if (i < 1024){ // w3 [16 x 64], tiles = ks
        const int ks = tile;
        const float v = w3[lr*64 + 16*ks + 4*lg + e];
        const _Float16 hh = (_Float16)v;
        w3Ah[i] = hh; w3Al[i] = (_Float16)(v - (float)hh);
    }
}

// global max of x0 ch3 -> slot; initial mask (u8) all-ones
__global__ __launch_bounds__(256) void prep_kernel(const float* __restrict__ x3,
    unsigned char* __restrict__ maskA, unsigned* __restrict__ slot)
{
    const int idx = blockIdx.x*256 + threadIdx.x;
    maskA[idx] = 1;
    float v = x3[idx];
    #pragma unroll
    for (int o=32;o;o>>=1) v = fmaxf(v, __shfl_down(v, o));
    __shared__ float red[4];
    const int lane = threadIdx.x & 63, wid = threadIdx.x >> 6;
    if (lane==0) red[wid]=v;
    __syncthreads();
    if (threadIdx.x==0){
        float m = fmaxf(fmaxf(red[0],red[1]), fmaxf(red[2],red[3]));
        atomicMax(slot, encf(m));
    }
}

struct XBuf { float x[16]; float m; int v; };

__device__ __forceinline__ void prefetch_t(int t, int d, int h, int w,
    const float* __restrict__ xin, const unsigned char* __restrict__ min_, XBuf& B)
{
    const int zz = d + t/9 - 1;
    const int yy = h + (t/3)%3 - 1;
    const int xx = w + t%3 - 1;
    const int zc = clampi(zz), yc = clampi(yy), xc = clampi(xx);
    B.v = (zz==zc) & (yy==yc) & (xx==xc);
    const int noff = zc*DSTRIDE + yc*Dn + xc;
    B.m = (float)min_[noff];
    #pragma unroll
    for (int c=0;c<16;++c) B.x[c] = xin[(size_t)c*Sn + noff];
}

__device__ __forceinline__ void accum_t(int t, const XBuf& A,
    const float* __restrict__ wpT, v2f* pv)
{
    const float mv = A.v ? A.m : 0.0f;
    const v2f mvv = {mv, mv};
    const float* wrow = wpT + t*48;
    #pragma unroll
    for (int i=0;i<8;++i){
        v2f xv = {A.x[2*i], A.x[2*i+1]};
        v2f xm = xv * mvv;                               // v_pk_mul_f32
        pv[i]    = __builtin_elementwise_fma(ld2(wrow + 2*i),      xm, pv[i]);
        pv[8+i]  = __builtin_elementwise_fma(ld2(wrow + 16 + 2*i), xm, pv[8+i]);
        pv[16+i] = __builtin_elementwise_fma(ld2(wrow + 32 + 2*i), xm, pv[16+i]);
    }
}

// fused: masked stencil dwconv (R2 coalesced thread<->voxel mapping) ->
// ONE LDS bridge (p as f32, wave-private rows, 16B-aligned rows, b128 ops) ->
// register-chained MLP 48->64->64->16 (weights-as-A; C-frag of each GEMM IS
// the next GEMM's B-frag, zero data movement) -> c3 back through same LDS
// rows (cols 0..15, p already consumed) -> R2 coalesced residual + store.
// ZERO barriers (all LDS rows wave-private). LDS 53248 B -> 2 blocks/CU.
// launch_bounds (256,2): VGPR cap 256 -> NO SPILLS (R4/R5/R7's hidden cost:
// tighter caps spilled the ~130-reg MLP live set to scratch; WRITE_SIZE
// 0.29-3.6 GB vs 57 MB ideal tracked cap tightness, not store pattern).
__global__ __launch_bounds__(256, 2) void update_kernel(
    const float* __restrict__ xin, const unsigned char* __restrict__ min_,
    float* __restrict__ xout,
    const float* __restrict__ wpT, const float* __restrict__ bpP,
    const _Float16* __restrict__ w1Ah, const _Float16* __restrict__ w1Al,
    const float* __restrict__ b1,
    const _Float16* __restrict__ w2Ah, const _Float16* __restrict__ w2Al,
    const float* __restrict__ b2,
    const _Float16* __restrict__ w3Ah, const _Float16* __restrict__ w3Al,
    const float* __restrict__ b3,
    unsigned* __restrict__ slot_post)
{
    __shared__ __align__(16) float sP[256*PSTR];   // 53248 B

    const int tid = threadIdx.x;
    const int w = blockIdx.x*32 + (tid & 31);
    const int h = blockIdx.y*8  + (tid >> 5);
    const int d = blockIdx.z;
    const int idx = d*DSTRIDE + h*Dn + w;

    const int lane = tid & 63;
    const int wv   = tid >> 6;       // wave id 0..3
    const int lr   = lane & 15;
    const int lg   = lane >> 4;

    // ---------------- stencil dwconv (R2 fp32 path, coalesced) -------------
    v2f pv[24];
    #pragma unroll
    for (int j=0;j<24;++j) pv[j] = ld2(bpP + 2*j);

    XBuf A, B;
    prefetch_t(0, d, h, w, xin, min_, A);
    #pragma unroll 1
    for (int t=0; t<26; t+=2){
        prefetch_t(t+1, d, h, w, xin, min_, B);
        accum_t(t, A, wpT, pv);
        prefetch_t(t+2, d, h, w, xin, min_, A);
        accum_t(t+1, B, wpT, pv);
    }
    accum_t(26, A, wpT, pv);

    // p -> LDS row tid (f32, cols 0..47 in q*16+c order, b128 stores)
    {
        float* pr = sP + tid*PSTR;
        #pragma unroll
        for (int jj=0;jj<12;++jj){
            v4f t = {pv[2*jj].x, pv[2*jj].y, pv[2*jj+1].x, pv[2*jj+1].y};
            __builtin_memcpy(pr + 4*jj, &t, 16);
        }
    }

    // ---------------- register-chained MLP, two j-halves -------------------
    // wave rows: 64wv..64wv+63. half 0 -> rows 0..31 (r0,r0+16); half 1 -> 32..63.
    const int rowbase = 64*wv;
    #pragma unroll 1
    for (int half=0; half<2; ++half){
        const int r0 = rowbase + 32*half + lr;   // jj=0
        const int r1 = r0 + 16;                  // jj=1

        __builtin_amdgcn_s_setprio(1);
        // -------- GEMM1: c1 = W1 @ p + b1 ------------------------------
        v4f c1[4][2];
        #pragma unroll
        for (int mt=0;mt<4;++mt){
            v4f bb; __builtin_memcpy(&bb, b1 + 16*mt + 4*lg, 16);
            c1[mt][0]=bb; c1[mt][1]=bb;
        }
        #pragma unroll
        for (int ks=0;ks<3;++ks){
            v4h bh[2], bl[2];
            #pragma unroll
            for (int jj=0;jj<2;++jj){
                v4f P;
                __builtin_memcpy(&P, sP + (jj ? r1 : r0)*PSTR + 16*ks + 4*lg, 16);
                v4h hi = {(_Float16)P[0],(_Float16)P[1],(_Float16)P[2],(_Float16)P[3]};
                v4h lo = {(_Float16)(P[0]-(float)hi[0]), (_Float16)(P[1]-(float)hi[1]),
                          (_Float16)(P[2]-(float)hi[2]), (_Float16)(P[3]-(float)hi[3])};
                bh[jj]=hi; bl[jj]=lo;
            }
            #pragma unroll
            for (int mt=0;mt<4;++mt){
                v4h ah, al;
                __builtin_memcpy(&ah, w1Ah + ((mt*3+ks)*64 + lane)*4, 8);
                __builtin_memcpy(&al, w1Al + ((mt*3+ks)*64 + lane)*4, 8);
                #pragma unroll
                for (int jj=0;jj<2;++jj){
                    c1[mt][jj] = __builtin_amdgcn_mfma_f32_16x16x16f16(ah, bh[jj], c1[mt][jj],0,0,0);
                    c1[mt][jj] = __builtin_amdgcn_mfma_f32_16x16x16f16(al, bh[jj], c1[mt][jj],0,0,0);
                    c1[mt][jj] = __builtin_amdgcn_mfma_f32_16x16x16f16(ah, bl[jj], c1[mt][jj],0,0,0);
                }
            }
        }

        // -------- GEMM2: c2 = W2 @ tanh(c1) + b2 -----------------------
        v4f c2[4][2];
        #pragma unroll
        for (int mt=0;mt<4;++mt){
            v4f bb; __builtin_memcpy(&bb, b2 + 16*mt + 4*lg, 16);
            c2[mt][0]=bb; c2[mt][1]=bb;
        }
        #pragma unroll
        for (int ks=0;ks<4;++ks){
            v4h bh[2], bl[2];
            #pragma unroll
            for (int jj=0;jj<2;++jj){
                float t0=ftanh(c1[ks][jj][0]), t1=ftanh(c1[ks][jj][1]);
                float t2=ftanh(c1[ks][jj][2]), t3=ftanh(c1[ks][jj][3]);
                v4h hi = {(_Float16)t0,(_Float16)t1,(_Float16)t2,(_Float16)t3};
                v4h lo = {(_Float16)(t0-(float)hi[0]), (_Float16)(t1-(float)hi[1]),
                          (_Float16)(t2-(float)hi[2]), (_Float16)(t3-(float)hi[3])};
                bh[jj]=hi; bl[jj]=lo;
            }
            #pragma unroll
            for (int mt=0;mt<4;++mt){
                v4h ah, al;
                __builtin_memcpy(&ah, w2Ah + ((mt*4+ks)*64 + lane)*4, 8);
                __builtin_memcpy(&al, w2Al + ((mt*4+ks)*64 + lane)*4, 8);
                #pragma unroll
                for (int jj=0;jj<2;++jj){
                    c2[mt][jj] = __builtin_amdgcn_mfma_f32_16x16x16f16(ah, bh[jj], c2[mt][jj],0,0,0);
                    c2[mt][jj] = __builtin_amdgcn_mfma_f32_16x16x16f16(al, bh[jj], c2[mt][jj],0,0,0);
                    c2[mt][jj] = __builtin_amdgcn_mfma_f32_16x16x16f16(ah, bl[jj], c2[mt][jj],0,0,0);
                }
            }
        }

        // -------- GEMM3: c3 = W3 @ tanh(c2) + b3 -----------------------
        v4f c3[2];
        {
            v4f bb; __builtin_memcpy(&bb, b3 + 4*lg, 16);
            c3[0]=bb; c3[1]=bb;
        }
        #pragma unroll
        for (int ks=0;ks<4;++ks){
            v4h bh[2], bl[2];
            #pragma unroll
            for (int jj=0;jj<2;++jj){
                float t0=ftanh(c2[ks][jj][0]), t1=ftanh(c2[ks][jj][1]);
                float t2=ftanh(c2[ks][jj][2]), t3=ftanh(c2[ks][jj][3]);
                v4h hi = {(_Float16)t0,(_Float16)t1,(_Float16)t2,(_Float16)t3};
                v4h lo = {(_Float16)(t0-(float)hi[0]), (_Float16)(t1-(float)hi[1]),
                          (_Float16)(t2-(float)hi[2]), (_Float16)(t3-(float)hi[3])};
                bh[jj]=hi; bl[jj]=lo;
            }
            v4h ah, al;
            __builtin_memcpy(&ah, w3Ah + (ks*64 + lane)*4, 8);
            __builtin_memcpy(&al, w3Al + (ks*64 + lane)*4, 8);
            #pragma unroll
            for (int jj=0;jj<2;++jj){
                c3[jj] = __builtin_amdgcn_mfma_f32_16x16x16f16(ah, bh[jj], c3[jj],0,0,0);
                c3[jj] = __builtin_amdgcn_mfma_f32_16x16x16f16(al, bh[jj], c3[jj],0,0,0);
                c3[jj] = __builtin_amdgcn_mfma_f32_16x16x16f16(ah, bl[jj], c3[jj],0,0,0);
            }
        }
        __builtin_amdgcn_s_setprio(0);

        // c3 -> LDS cols 0..15 of rows r0/r1 (p there already consumed;
        // rows are wave-private -> no barrier); 16B writes
        __builtin_memcpy(sP + r0*PSTR + 4*lg, &c3[0], 16);
        __builtin_memcpy(sP + r1*PSTR + 4*lg, &c3[1], 16);
    }

    // ---------------- residual + coalesced channel-major store -------------
    const float mcen = (float)min_[idx];
    const float* orow = sP + tid*PSTR;
    float v3 = 0.0f;
    #pragma unroll
    for (int c=0;c<16;++c){
        const float xn = fmaf(xin[(size_t)c*Sn+idx], mcen, orow[c]);
        xout[(size_t)c*Sn+idx] = xn;
        if (c==3) v3 = xn;
    }

    #pragma unroll
    for (int o=32;o;o>>=1) v3 = fmaxf(v3, __shfl_down(v3, o));
    if ((tid & 63) == 0) atomicMax(slot_post, encf(v3));
}

// alive0 from masked old ch3 plane, alive1 from unmasked new ch3 plane
// (both contiguous, channel-major); life includes boundary zero
// x[:, :, -1, 48:, :]=0; also produces next step's pre-max.
__global__ __launch_bounds__(256) void mask_kernel(
    const float* __restrict__ x3old, const unsigned char* __restrict__ min_,
    const float* __restrict__ x3new, unsigned char* __restrict__ mout,
    const unsigned* __restrict__ slot_pre, const unsigned* __restrict__ slot_post,
    unsigned* __restrict__ slot_next)
{
    const int idx = blockIdx.x*256 + threadIdx.x;
    const int w = idx % Dn;
    const int h = (idx / Dn) % Dn;
    const int d = idx / DSTRIDE;
    const float th0 = 0.1f * decf(*slot_pre);
    const float th1 = 0.1f * decf(*slot_post);
    float a0 = -INFINITY, a1 = -INFINITY;
    #pragma unroll
    for (int t=0;t<27;++t){
        const int dz=t/9-1, dy=(t/3)%3-1, dx=t%3-1;
        const int zz=d+dz, yy=h+dy, xx=w+dx;
        if ((unsigned)zz<(unsigned)Dn && (unsigned)yy<(unsigned)Dn &&
            (unsigned)xx<(unsigned)Dn){
            const int noff = idx + dz*DSTRIDE + dy*Dn + dx;
            a0 = fmaxf(a0, x3old[noff] * (float)min_[noff]);
            a1 = fmaxf(a1, x3new[noff]);
        }
    }
    const bool life = (a0 > th0) && (a1 > th1) && !(d==Dn-1 && h>=48);
    mout[idx] = life ? 1 : 0;
    const float mv = life ? 1.0f : 0.0f;

    float f3 = x3new[idx]*mv;   // final ch3 value -> pre-max of next step
    #pragma unroll
    for (int o=32;o;o>>=1) f3 = fmaxf(f3, __shfl_down(f3, o));
    __shared__ float red[4];
    const int lane = threadIdx.x & 63, wid = threadIdx.x >> 6;
    if (lane==0) red[wid]=f3;
    __syncthreads();
    if (threadIdx.x==0){
        float m = fmaxf(fmaxf(red[0],red[1]), fmaxf(red[2],red[3]));
        atomicMax(slot_next, encf(m));
    }
}

// final: apply last step's mask in place on d_out (channel-major)
__global__ __launch_bounds__(256) void apply_kernel(float* __restrict__ x,
    const unsigned char* __restrict__ mk)
{
    const int idx = blockIdx.x*256 + threadIdx.x;
    const float m = (float)mk[idx];
    #pragma unroll
    for (int c=0;c<Cn;++c) x[(size_t)c*Sn+idx] *= m;
}

extern "C" void kernel_launch(void* const* d_in, const int* in_sizes, int n_in,
                              void* d_out, int out_size, void* d_ws, size_t ws_size,
                              hipStream_t stream)
{
    const float* x0 = (const float*)d_in[0];
    const float* wp = (const float*)d_in[1];
    const float* bp = (const float*)d_in[2];
    const float* w1 = (const float*)d_in[3];
    const float* b1 = (const float*)d_in[4];
    const float* w2 = (const float*)d_in[5];
    const float* b2 = (const float*)d_in[6];
    const float* w3 = (const float*)d_in[7];
    const float* b3 = (const float*)d_in[8];
    float* out = (float*)d_out;

    // ws: T0 16*Sn f32 | maskA,maskB u8 Sn each | maxv | wpT 1296 f | bpP 48 f |
    //     A-frag packs 16384 h (32 KB)
    float* T0 = (float*)d_ws;
    unsigned char* mA = (unsigned char*)(T0 + (size_t)Cn*Sn);
    unsigned char* mB = mA + Sn;
    unsigned* maxv = (unsigned*)(mB + Sn);
    float* wpT = (float*)(maxv + 16);
    float* bpP = wpT + 1296;
    _Float16* w1Ah = (_Float16*)(bpP + 48);
    _Float16* w1Al = w1Ah + 3072;
    _Float16* w2Ah = w1Al + 3072;
    _Float16* w2Al = w2Ah + 4096;
    _Float16* w3Ah = w2Al + 4096;
    _Float16* w3Al = w3Ah + 1024;

    init_kernel<<<1, 64, 0, stream>>>(maxv);
    tr_kernel<<<6, 256, 0, stream>>>(wp, bp, wpT, bpP);
    pack_kernel<<<16, 256, 0, stream>>>(w1, w2, w3, w1Ah, w1Al, w2Ah, w2Al, w3Ah, w3Al);
    prep_kernel<<<Sn/256, 256, 0, stream>>>(x0 + (size_t)3*Sn, mA, &maxv[0]);

    // all states channel-major; ping-pong T0(ws) <-> d_out; step 3 ends in d_out
    const float* xi[4] = {x0, T0, out, T0};
    float*       xo[4] = {T0, out, T0, out};
    const unsigned char* mi[4] = {mA, mB, mA, mB};
    unsigned char*       mo[4] = {mB, mA, mB, mA};

    dim3 ugrid(Dn/32, Dn/8, Dn);
    for (int s=0; s<4; ++s){
        update_kernel<<<ugrid, 256, 0, stream>>>(xi[s], mi[s], xo[s],
            wpT, bpP, w1Ah, w1Al, b1, w2Ah, w2Al, b2, w3Ah, w3Al, b3, &maxv[2*s+1]);
        mask_kernel<<<Sn/256, 256, 0, stream>>>(xi[s] + (size_t)3*Sn, mi[s],
            xo[s] + (size_t)3*Sn, mo[s], &maxv[2*s], &maxv[2*s+1], &maxv[2*s+2]);
    }
    apply_kernel<<<Sn/256, 256, 0, stream>>>(out, mA);
}

// Round 9
// 1325.054 us; speedup vs baseline: 5.9930x; 1.0732x over previous
//
#include <hip/hip_runtime.h>

#define Cn 16
#define Dn 96
#define Sn (Dn*Dn*Dn)        /* 884736 */
#define DSTRIDE (Dn*Dn)      /* 9216 */
#define ENC_NEG_INF 0x007FFFFFu
#define PSTR 52              /* LDS row stride in f32: 208 B, 16B-aligned; 20*row%32 -> 8 bank starts (conflicts measured small) */

typedef float v2f __attribute__((ext_vector_type(2)));
typedef float v4f __attribute__((ext_vector_type(4)));
typedef _Float16 v4h __attribute__((ext_vector_type(4)));

__device__ __forceinline__ v2f ld2(const float* p){
    v2f r; __builtin_memcpy(&r, p, 8); return r;
}
// monotonic float<->uint map for atomicMax on signed floats
__device__ __forceinline__ unsigned encf(float f){
    unsigned u = __float_as_uint(f);
    return (u & 0x80000000u) ? ~u : (u | 0x80000000u);
}
__device__ __forceinline__ float decf(unsigned u){
    return (u & 0x80000000u) ? __uint_as_float(u ^ 0x80000000u) : __uint_as_float(~u);
}
// tanh(x) = 1 - 2/(exp(2x)+1)
__device__ __forceinline__ float ftanh(float x){
    float t = __expf(2.0f*x);
    return 1.0f - __fdividef(2.0f, t + 1.0f);
}
__device__ __forceinline__ int clampi(int v){ return v<0?0:(v>Dn-1?Dn-1:v); }

__global__ void init_kernel(unsigned* __restrict__ maxv){
    if (threadIdx.x < 16) maxv[threadIdx.x] = ENC_NEG_INF;
}

// Stencil weight reorder (once):
//  wpT[t*48+q*16+c]=wp[(3c+q)*27+t]; bpP[q*16+c]=bp[3c+q]
__global__ void tr_kernel(const float* __restrict__ wp, const float* __restrict__ bp,
                          float* __restrict__ wpT, float* __restrict__ bpP){
    const int i = blockIdx.x*256 + threadIdx.x;
    if (i < 1296){ const int t=i/48, r=i%48, q=r>>4, c=r&15; wpT[i] = wp[(3*c+q)*27 + t]; }
    if (i < 48)  { const int q=i>>4, c=i&15; bpP[i] = bp[3*c + q]; }
}

// Pack MLP weights as MFMA *A*-fragments (M=out-feature, K=in-feature),
// split hi/lo f16 (3-term split-f16 GEMM ~ fp32 accuracy).
// A-frag tile (mt,ks): lane l elem e holds A[m=16mt+(l&15)][k=16ks+4*(l>>4)+e].
// Layer-1 k runs over the PERMUTED dwconv index j=q*16+c (orig = 3c+q), q=ks.
// (verified correct in R4/R5/R7/R8 runs, absmax 0.03125)
__global__ void pack_kernel(const float* __restrict__ w1, const float* __restrict__ w2,
                            const float* __restrict__ w3,
                            _Float16* __restrict__ w1Ah, _Float16* __restrict__ w1Al,
                            _Float16* __restrict__ w2Ah, _Float16* __restrict__ w2Al,
                            _Float16* __restrict__ w3Ah, _Float16* __restrict__ w3Al){
    const int i = blockIdx.x*256 + threadIdx.x;
    const int e = i & 3, l = (i>>2) & 63, tile = i >> 8;
    const int lr = l & 15, lg = l >> 4;
    if (i < 3072){ // w1 [64 out x 48 in], tiles = mt*3+ks
        const int ks = tile % 3, mt = tile / 3;
        const int c = 4*lg + e;                       // k = 16ks + 4lg + e -> q=ks, c
        const float v = w1[(16*mt + lr)*48 + 3*c + ks];
        const _Float16 hh = (_Float16)v;
        w1Ah[i] = hh; w1Al[i] = (_Float16)(v - (float)hh);
    }
    if (i < 4096){ // w2 [64 x 64], tiles = mt*4+ks
        const int ks = tile & 3, mt = tile >> 2;
        const float v = w2[(16*mt + lr)*64 + 16*ks + 4*lg + e];
        const _Float16 hh = (_Float16)v;
        w2Ah[i] = hh; w2Al[i] = (_Float16)(v - (float)hh);
    }
    if (i < 1024){ // w3 [16 x 64], tiles = ks
        const int ks = tile;
        const float v = w3[lr*64 + 16*ks + 4*lg + e];
        const _Float16 hh = (_Float16)v;
        w3Ah[i] = hh; w3Al[i] = (_Float16)(v - (float)hh);
    }
}

// global max of x0 ch3 -> slot; initial mask (u8) all-ones
__global__ __launch_bounds__(256) void prep_kernel(const float* __restrict__ x3,
    unsigned char* __restrict__ maskA, unsigned* __restrict__ slot)
{
    const int idx = blockIdx.x*256 + threadIdx.x;
    maskA[idx] = 1;
    float v = x3[idx];
    #pragma unroll
    for (int o=32;o;o>>=1) v = fmaxf(v, __shfl_down(v, o));
    __shared__ float red[4];
    const int lane = threadIdx.x & 63, wid = threadIdx.x >> 6;
    if (lane==0) red[wid]=v;
    __syncthreads();
    if (threadIdx.x==0){
        float m = fmaxf(fmaxf(red[0],red[1]), fmaxf(red[2],red[3]));
        atomicMax(slot, encf(m));
    }
}

// one-time transpose x0 [16][Sn] -> xT [4][Sn][4] (channel-tiled):
// element (g,idx,e) at (g*Sn+idx)*4+e. Writes: per g, lane idx consecutive
// -> 16B x 64 lanes = 1KB contiguous.
__global__ __launch_bounds__(256) void transpose_kernel(const float* __restrict__ x,
    float* __restrict__ xT)
{
    const int idx = blockIdx.x*256 + threadIdx.x;
    float v[16];
    #pragma unroll
    for (int c=0;c<16;++c) v[c] = x[(size_t)c*Sn + idx];
    #pragma unroll
    for (int g=0;g<4;++g){
        v4f t = {v[4*g], v[4*g+1], v[4*g+2], v[4*g+3]};
        __builtin_memcpy(xT + ((size_t)g*Sn + idx)*4, &t, 16);
    }
}

struct XBufT { v4f x[4]; float m; int v; };

__device__ __forceinline__ void prefetch_t(int t, int d, int h, int w,
    const float* __restrict__ xt, const unsigned char* __restrict__ min_, XBufT& B)
{
    const int zz = d + t/9 - 1;
    const int yy = h + (t/3)%3 - 1;
    const int xx = w + t%3 - 1;
    const int zc = clampi(zz), yc = clampi(yy), xc = clampi(xx);
    B.v = (zz==zc) & (yy==yc) & (xx==xc);
    const int noff = zc*DSTRIDE + yc*Dn + xc;
    B.m = (float)min_[noff];
    #pragma unroll
    for (int g=0;g<4;++g)
        __builtin_memcpy(&B.x[g], xt + ((size_t)g*Sn + noff)*4, 16);
}

__device__ __forceinline__ void accum_t(int t, const XBufT& A,
    const float* __restrict__ wpT, v2f* pv)
{
    const float mv = A.v ? A.m : 0.0f;
    const v2f mvv = {mv, mv};
    const float* wrow = wpT + t*48;
    #pragma unroll
    for (int i=0;i<8;++i){
        v2f xv = { A.x[i>>1][2*(i&1)], A.x[i>>1][2*(i&1)+1] };
        v2f xm = xv * mvv;                               // v_pk_mul_f32
        pv[i]    = __builtin_elementwise_fma(ld2(wrow + 2*i),      xm, pv[i]);
        pv[8+i]  = __builtin_elementwise_fma(ld2(wrow + 16 + 2*i), xm, pv[8+i]);
        pv[16+i] = __builtin_elementwise_fma(ld2(wrow + 32 + 2*i), xm, pv[16+i]);
    }
}

// fused: masked stencil dwconv (channel-tiled dwordx4 loads: 4 instrs/tap,
// 1KB contiguous per wave-instr) -> ONE LDS bridge (p f32, wave-private rows)
// -> register-chained MLP 48->64->64->16 (weights-as-A; C-frag IS next B-frag)
// -> c3 back through same LDS rows -> tiled residual+store (+ch3 plane).
// ZERO barriers. launch_bounds (256,2): VGPR cap 256 -> NO spills (R8 lesson:
// tighter caps spill the ~130-reg MLP live set; WRITE_SIZE then explodes).
__global__ __launch_bounds__(256, 2) void update_kernel(
    const float* __restrict__ xinT, const unsigned char* __restrict__ min_,
    float* __restrict__ xout, const int final_, float* __restrict__ x3out,
    const float* __restrict__ wpT, const float* __restrict__ bpP,
    const _Float16* __restrict__ w1Ah, const _Float16* __restrict__ w1Al,
    const float* __restrict__ b1,
    const _Float16* __restrict__ w2Ah, const _Float16* __restrict__ w2Al,
    const float* __restrict__ b2,
    const _Float16* __restrict__ w3Ah, const _Float16* __restrict__ w3Al,
    const float* __restrict__ b3,
    unsigned* __restrict__ slot_post)
{
    __shared__ __align__(16) float sP[256*PSTR];   // 53248 B

    const int tid = threadIdx.x;
    const int w = blockIdx.x*32 + (tid & 31);
    const int h = blockIdx.y*8  + (tid >> 5);
    const int d = blockIdx.z;
    const int idx = d*DSTRIDE + h*Dn + w;

    const int lane = tid & 63;
    const int wv   = tid >> 6;       // wave id 0..3
    const int lr   = lane & 15;
    const int lg   = lane >> 4;

    // ---------------- stencil dwconv (tiled dwordx4 loads) -----------------
    v2f pv[24];
    #pragma unroll
    for (int j=0;j<24;++j) pv[j] = ld2(bpP + 2*j);

    XBufT A, B;
    prefetch_t(0, d, h, w, xinT, min_, A);
    #pragma unroll 1
    for (int t=0; t<26; t+=2){
        prefetch_t(t+1, d, h, w, xinT, min_, B);
        accum_t(t, A, wpT, pv);
        prefetch_t(t+2, d, h, w, xinT, min_, A);
        accum_t(t+1, B, wpT, pv);
    }
    accum_t(26, A, wpT, pv);

    // p -> LDS row tid (f32, cols 0..47 in q*16+c order, b128 stores)
    {
        float* pr = sP + tid*PSTR;
        #pragma unroll
        for (int jj=0;jj<12;++jj){
            v4f t = {pv[2*jj].x, pv[2*jj].y, pv[2*jj+1].x, pv[2*jj+1].y};
            __builtin_memcpy(pr + 4*jj, &t, 16);
        }
    }

    // ---------------- register-chained MLP, two j-halves -------------------
    const int rowbase = 64*wv;
    #pragma unroll 1
    for (int half=0; half<2; ++half){
        const int r0 = rowbase + 32*half + lr;   // jj=0
        const int r1 = r0 + 16;                  // jj=1

        __builtin_amdgcn_s_setprio(1);
        // -------- GEMM1: c1 = W1 @ p + b1 ------------------------------
        v4f c1[4][2];
        #pragma unroll
        for (int mt=0;mt<4;++mt){
            v4f bb; __builtin_memcpy(&bb, b1 + 16*mt + 4*lg, 16);
            c1[mt][0]=bb; c1[mt][1]=bb;
        }
        #pragma unroll
        for (int ks=0;ks<3;++ks){
            v4h bh[2], bl[2];
            #pragma unroll
            for (int jj=0;jj<2;++jj){
                v4f P;
                __builtin_memcpy(&P, sP + (jj ? r1 : r0)*PSTR + 16*ks + 4*lg, 16);
                v4h hi = {(_Float16)P[0],(_Float16)P[1],(_Float16)P[2],(_Float16)P[3]};
                v4h lo = {(_Float16)(P[0]-(float)hi[0]), (_Float16)(P[1]-(float)hi[1]),
                          (_Float16)(P[2]-(float)hi[2]), (_Float16)(P[3]-(float)hi[3])};
                bh[jj]=hi; bl[jj]=lo;
            }
            #pragma unroll
            for (int mt=0;mt<4;++mt){
                v4h ah, al;
                __builtin_memcpy(&ah, w1Ah + ((mt*3+ks)*64 + lane)*4, 8);
                __builtin_memcpy(&al, w1Al + ((mt*3+ks)*64 + lane)*4, 8);
                #pragma unroll
                for (int jj=0;jj<2;++jj){
                    c1[mt][jj] = __builtin_amdgcn_mfma_f32_16x16x16f16(ah, bh[jj], c1[mt][jj],0,0,0);
                    c1[mt][jj] = __builtin_amdgcn_mfma_f32_16x16x16f16(al, bh[jj], c1[mt][jj],0,0,0);
                    c1[mt][jj] = __builtin_amdgcn_mfma_f32_16x16x16f16(ah, bl[jj], c1[mt][jj],0,0,0);
                }
            }
        }

        // -------- GEMM2: c2 = W2 @ tanh(c1) + b2 -----------------------
        v4f c2[4][2];
        #pragma unroll
        for (int mt=0;mt<4;++mt){
            v4f bb; __builtin_memcpy(&bb, b2 + 16*mt + 4*lg, 16);
            c2[mt][0]=bb; c2[mt][1]=bb;
        }
        #pragma unroll
        for (int ks=0;ks<4;++ks){
            v4h bh[2], bl[2];
            #pragma unroll
            for (int jj=0;jj<2;++jj){
                float t0=ftanh(c1[ks][jj][0]), t1=ftanh(c1[ks][jj][1]);
                float t2=ftanh(c1[ks][jj][2]), t3=ftanh(c1[ks][jj][3]);
                v4h hi = {(_Float16)t0,(_Float16)t1,(_Float16)t2,(_Float16)t3};
                v4h lo = {(_Float16)(t0-(float)hi[0]), (_Float16)(t1-(float)hi[1]),
                          (_Float16)(t2-(float)hi[2]), (_Float16)(t3-(float)hi[3])};
                bh[jj]=hi; bl[jj]=lo;
            }
            #pragma unroll
            for (int mt=0;mt<4;++mt){
                v4h ah, al;
                __builtin_memcpy(&ah, w2Ah + ((mt*4+ks)*64 + lane)*4, 8);
                __builtin_memcpy(&al, w2Al + ((mt*4+ks)*64 + lane)*4, 8);
                #pragma unroll
                for (int jj=0;jj<2;++jj){
                    c2[mt][jj] = __builtin_amdgcn_mfma_f32_16x16x16f16(ah, bh[jj], c2[mt][jj],0,0,0);
                    c2[mt][jj] = __builtin_amdgcn_mfma_f32_16x16x16f16(al, bh[jj], c2[mt][jj],0,0,0);
                    c2[mt][jj] = __builtin_amdgcn_mfma_f32_16x16x16f16(ah, bl[jj], c2[mt][jj],0,0,0);
                }
            }
        }

        // -------- GEMM3: c3 = W3 @ tanh(c2) + b3 -----------------------
        v4f c3[2];
        {
            v4f bb; __builtin_memcpy(&bb, b3 + 4*lg, 16);
            c3[0]=bb; c3[1]=bb;
        }
        #pragma unroll
        for (int ks=0;ks<4;++ks){
            v4h bh[2], bl[2];
            #pragma unroll
            for (int jj=0;jj<2;++jj){
                float t0=ftanh(c2[ks][jj][0]), t1=ftanh(c2[ks][jj][1]);
                float t2=ftanh(c2[ks][jj][2]), t3=ftanh(c2[ks][jj][3]);
                v4h hi = {(_Float16)t0,(_Float16)t1,(_Float16)t2,(_Float16)t3};
                v4h lo = {(_Float16)(t0-(float)hi[0]), (_Float16)(t1-(float)hi[1]),
                          (_Float16)(t2-(float)hi[2]), (_Float16)(t3-(float)hi[3])};
                bh[jj]=hi; bl[jj]=lo;
            }
            v4h ah, al;
            __builtin_memcpy(&ah, w3Ah + (ks*64 + lane)*4, 8);
            __builtin_memcpy(&al, w3Al + (ks*64 + lane)*4, 8);
            #pragma unroll
            for (int jj=0;jj<2;++jj){
                c3[jj] = __builtin_amdgcn_mfma_f32_16x16x16f16(ah, bh[jj], c3[jj],0,0,0);
                c3[jj] = __builtin_amdgcn_mfma_f32_16x16x16f16(al, bh[jj], c3[jj],0,0,0);
                c3[jj] = __builtin_amdgcn_mfma_f32_16x16x16f16(ah, bl[jj], c3[jj],0,0,0);
            }
        }
        __builtin_amdgcn_s_setprio(0);

        // c3 -> LDS cols 0..15 of rows r0/r1 (wave-private; no barrier)
        __builtin_memcpy(sP + r0*PSTR + 4*lg, &c3[0], 16);
        __builtin_memcpy(sP + r1*PSTR + 4*lg, &c3[1], 16);
    }

    // ---------------- residual + tiled store (+ ch3 plane & max) -----------
    const float mcen = (float)min_[idx];
    const float* orow = sP + tid*PSTR;
    float v3 = 0.0f;
    if (!final_){
        #pragma unroll
        for (int g=0;g<4;++g){
            v4f xc; __builtin_memcpy(&xc, xinT + ((size_t)g*Sn + idx)*4, 16);
            v4f xn;
            #pragma unroll
            for (int e=0;e<4;++e) xn[e] = fmaf(xc[e], mcen, orow[4*g+e]);
            __builtin_memcpy(xout + ((size_t)g*Sn + idx)*4, &xn, 16);
            if (g==0) v3 = xn[3];
        }
        if (x3out) x3out[idx] = v3;
    } else {
        #pragma unroll
        for (int g=0;g<4;++g){
            v4f xc; __builtin_memcpy(&xc, xinT + ((size_t)g*Sn + idx)*4, 16);
            #pragma unroll
            for (int e=0;e<4;++e){
                const float xn = fmaf(xc[e], mcen, orow[4*g+e]);
                xout[(size_t)(4*g+e)*Sn + idx] = xn;
                if (g==0 && e==3) v3 = xn;
            }
        }
    }

    #pragma unroll
    for (int o=32;o;o>>=1) v3 = fmaxf(v3, __shfl_down(v3, o));
    if ((tid & 63) == 0) atomicMax(slot_post, encf(v3));
}

// alive0 from masked old ch3, alive1 from unmasked new ch3; sources are
// contiguous planes (a*_t=0) or channel-tiled (a*_t=1: ch3 at [noff*4+3]).
__global__ __launch_bounds__(256) void mask_kernel(
    const float* __restrict__ a0src, const int a0_t,
    const unsigned char* __restrict__ min_,
    const float* __restrict__ a1src, const int a1_t,
    unsigned char* __restrict__ mout,
    const unsigned* __restrict__ slot_pre, const unsigned* __restrict__ slot_post,
    unsigned* __restrict__ slot_next)
{
    const int idx = blockIdx.x*256 + threadIdx.x;
    const int w = idx % Dn;
    const int h = (idx / Dn) % Dn;
    const int d = idx / DSTRIDE;
    const float th0 = 0.1f * decf(*slot_pre);
    const float th1 = 0.1f * decf(*slot_post);
    float a0 = -INFINITY, a1 = -INFINITY;
    #pragma unroll
    for (int t=0;t<27;++t){
        const int dz=t/9-1, dy=(t/3)%3-1, dx=t%3-1;
        const int zz=d+dz, yy=h+dy, xx=w+dx;
        if ((unsigned)zz<(unsigned)Dn && (unsigned)yy<(unsigned)Dn &&
            (unsigned)xx<(unsigned)Dn){
            const int noff = idx + dz*DSTRIDE + dy*Dn + dx;
            const float x0v = a0_t ? a0src[(size_t)noff*4+3] : a0src[noff];
            const float x1v = a1_t ? a1src[(size_t)noff*4+3] : a1src[noff];
            a0 = fmaxf(a0, x0v * (float)min_[noff]);
            a1 = fmaxf(a1, x1v);
        }
    }
    const bool life = (a0 > th0) && (a1 > th1) && !(d==Dn-1 && h>=48);
    mout[idx] = life ? 1 : 0;
    const float mv = life ? 1.0f : 0.0f;

    const float xv3 = a1_t ? a1src[(size_t)idx*4+3] : a1src[idx];
    float f3 = xv3*mv;   // final ch3 value -> pre-max of next step
    #pragma unroll
    for (int o=32;o;o>>=1) f3 = fmaxf(f3, __shfl_down(f3, o));
    __shared__ float red[4];
    const int lane = threadIdx.x & 63, wid = threadIdx.x >> 6;
    if (lane==0) red[wid]=f3;
    __syncthreads();
    if (threadIdx.x==0){
        float m = fmaxf(fmaxf(red[0],red[1]), fmaxf(red[2],red[3]));
        atomicMax(slot_next, encf(m));
    }
}

// final: apply last step's mask in place on d_out (channel-major)
__global__ __launch_bounds__(256) void apply_kernel(float* __restrict__ x,
    const unsigned char* __restrict__ mk)
{
    const int idx = blockIdx.x*256 + threadIdx.x;
    const float m = (float)mk[idx];
    #pragma unroll
    for (int c=0;c<Cn;++c) x[(size_t)c*Sn+idx] *= m;
}

extern "C" void kernel_launch(void* const* d_in, const int* in_sizes, int n_in,
                              void* d_out, int out_size, void* d_ws, size_t ws_size,
                              hipStream_t stream)
{
    const float* x0 = (const float*)d_in[0];
    const float* wp = (const float*)d_in[1];
    const float* bp = (const float*)d_in[2];
    const float* w1 = (const float*)d_in[3];
    const float* b1 = (const float*)d_in[4];
    const float* w2 = (const float*)d_in[5];
    const float* b2 = (const float*)d_in[6];
    const float* w3 = (const float*)d_in[7];
    const float* b3 = (const float*)d_in[8];
    float* out = (float*)d_out;

    // ws: T0 16*Sn f32 | maskA,maskB u8 Sn each | maxv | wpT 1296 f | bpP 48 f |
    //     A-frag packs 16384 h | [P0,P1 ch3 planes Sn f32 each, if ws allows]
    float* T0 = (float*)d_ws;
    unsigned char* mA = (unsigned char*)(T0 + (size_t)Cn*Sn);
    unsigned char* mB = mA + Sn;
    unsigned* maxv = (unsigned*)(mB + Sn);
    float* wpT = (float*)(maxv + 16);
    float* bpP = wpT + 1296;
    _Float16* w1Ah = (_Float16*)(bpP + 48);
    _Float16* w1Al = w1Ah + 3072;
    _Float16* w2Ah = w1Al + 3072;
    _Float16* w2Al = w2Ah + 4096;
    _Float16* w3Ah = w2Al + 4096;
    _Float16* w3Al = w3Ah + 1024;
    float* Pbase = (float*)(w3Al + 1024);
    const size_t need = (size_t)((char*)(Pbase + 2*(size_t)Sn) - (char*)d_ws);
    const bool planes = (ws_size >= need);
    float* P[2] = { Pbase, Pbase + Sn };
    float* T1 = out;   // d_out doubles as the second tiled state buffer

    init_kernel<<<1, 64, 0, stream>>>(maxv);
    tr_kernel<<<6, 256, 0, stream>>>(wp, bp, wpT, bpP);
    pack_kernel<<<16, 256, 0, stream>>>(w1, w2, w3, w1Ah, w1Al, w2Ah, w2Al, w3Ah, w3Al);
    prep_kernel<<<Sn/256, 256, 0, stream>>>(x0 + (size_t)3*Sn, mA, &maxv[0]);
    transpose_kernel<<<Sn/256, 256, 0, stream>>>(x0, T1);

    // steps 0-2 ping-pong channel-tiled between T1(d_out) and T0(ws);
    // step 3 reads T0, writes channel-major to d_out.
    const float* xiT[4] = {T1, T0, T1, T0};
    float*       xo[4]  = {T0, T1, T0, out};
    const int    fin[4] = {0, 0, 0, 1};
    const unsigned char* mi[4] = {mA, mB, mA, mB};
    unsigned char*       mo[4] = {mB, mA, mB, mA};

    dim3 ugrid(Dn/32, Dn/8, Dn);
    for (int s=0; s<4; ++s){
        float* x3o = (planes && s<3) ? P[s&1] : nullptr;
        update_kernel<<<ugrid, 256, 0, stream>>>(xiT[s], mi[s], xo[s], fin[s], x3o,
            wpT, bpP, w1Ah, w1Al, b1, w2Ah, w2Al, b2, w3Ah, w3Al, b3, &maxv[2*s+1]);

        const float* a0src; int a0t;
        if (s==0){ a0src = x0 + (size_t)3*Sn; a0t = 0; }
        else if (planes){ a0src = P[(s-1)&1]; a0t = 0; }
        else { a0src = xiT[s]; a0t = 1; }
        const float* a1src; int a1t;
        if (s==3){ a1src = out + (size_t)3*Sn; a1t = 0; }
        else if (planes){ a1src = P[s&1]; a1t = 0; }
        else { a1src = xo[s]; a1t = 1; }

        mask_kernel<<<Sn/256, 256, 0, stream>>>(a0src, a0t, mi[s], a1src, a1t,
            mo[s], &maxv[2*s], &maxv[2*s+1], &maxv[2*s+2]);
    }
    apply_kernel<<<Sn/256, 256, 0, stream>>>(out, mA);
}

// Round 11
// 1307.416 us; speedup vs baseline: 6.0739x; 1.0135x over previous
//
#include <hip/hip_runtime.h>

#define Cn 16
#define Dn 96
#define Sn (Dn*Dn*Dn)        /* 884736 */
#define DSTRIDE (Dn*Dn)      /* 9216 */
#define ENC_NEG_INF 0x007FFFFFu
#define PSTR 52              /* LDS row stride in f32: 208 B, 16B-aligned */

typedef float v2f __attribute__((ext_vector_type(2)));
typedef float v4f __attribute__((ext_vector_type(4)));
typedef _Float16 v4h __attribute__((ext_vector_type(4)));
typedef _Float16 v8h __attribute__((ext_vector_type(8)));

__device__ __forceinline__ v2f ld2(const float* p){
    v2f r; __builtin_memcpy(&r, p, 8); return r;
}
// monotonic float<->uint map for atomicMax on signed floats
__device__ __forceinline__ unsigned encf(float f){
    unsigned u = __float_as_uint(f);
    return (u & 0x80000000u) ? ~u : (u | 0x80000000u);
}
__device__ __forceinline__ float decf(unsigned u){
    return (u & 0x80000000u) ? __uint_as_float(u ^ 0x80000000u) : __uint_as_float(~u);
}
// tanh(x) = 1 - 2/(exp(2x)+1)
__device__ __forceinline__ float ftanh(float x){
    float t = __expf(2.0f*x);
    return 1.0f - __fdividef(2.0f, t + 1.0f);
}
__device__ __forceinline__ int clampi(int v){ return v<0?0:(v>Dn-1?Dn-1:v); }

__global__ void init_kernel(unsigned* __restrict__ maxv){
    if (threadIdx.x < 16) maxv[threadIdx.x] = ENC_NEG_INF;
}

// Stencil weight reorder (once):
//  wpT[t*48+q*16+c]=wp[(3c+q)*27+t]; bpP[q*16+c]=bp[3c+q]
__global__ void tr_kernel(const float* __restrict__ wp, const float* __restrict__ bp,
                          float* __restrict__ wpT, float* __restrict__ bpP){
    const int i = blockIdx.x*256 + threadIdx.x;
    if (i < 1296){ const int t=i/48, r=i%48, q=r>>4, c=r&15; wpT[i] = wp[(3*c+q)*27 + t]; }
    if (i < 48)  { const int q=i>>4, c=i&15; bpP[i] = bp[3*c + q]; }
}

// Pack MLP weights as MFMA *A*-fragments, FUSED hi/lo per lane:
// layout [tile][lane][8]: elems 0..3 = hi frag, 4..7 = lo frag -> ONE
// dwordx4 load per (tile,lane) yields both (halves weight VMEM issue).
// A-frag tile (mt,ks): lane l elem e holds A[m=16mt+(l&15)][k=16ks+4*(l>>4)+e].
// Layer-1 k runs over the PERMUTED dwconv index j=q*16+c (orig = 3c+q), q=ks.
// (fragment algebra verified in R4/R5/R7/R8/R9; fused layout audited R10/R11)
__global__ void pack_kernel(const float* __restrict__ w1, const float* __restrict__ w2,
                            const float* __restrict__ w3,
                            _Float16* __restrict__ w1F, _Float16* __restrict__ w2F,
                            _Float16* __restrict__ w3F){
    const int i = blockIdx.x*256 + threadIdx.x;
    const int e = i & 3, l = (i>>2) & 63, tile = i >> 8;
    const int lr = l & 15, lg = l >> 4;
    if (i < 3072){ // w1 [64 out x 48 in], tiles = mt*3+ks
        const int ks = tile % 3, mt = tile / 3;
        const int c = 4*lg + e;                       // k = 16ks + 4lg + e -> q=ks, c
        const float v = w1[(16*mt + lr)*48 + 3*c + ks];
        const _Float16 hh = (_Float16)v;
        const int base = (tile*64 + l)*8;
        w1F[base + e] = hh; w1F[base + 4 + e] = (_Float16)(v - (float)hh);
    }
    if (i < 4096){ // w2 [64 x 64], tiles = mt*4+ks
        const int ks = tile & 3, mt = tile >> 2;
        const float v = w2[(16*mt + lr)*64 + 16*ks + 4*lg + e];
        const _Float16 hh = (_Float16)v;
        const int base = (tile*64 + l)*8;
        w2F[base + e] = hh; w2F[base + 4 + e] = (_Float16)(v - (float)hh);
    }
    if (i < 1024){ // w3 [16 x 64], tiles = ks
        const int ks = tile;
        const float v = w3[lr*64 + 16*ks + 4*lg + e];
        const _Float16 hh = (_Float16)v;
        const int base = (tile*64 + l)*8;
        w3F[base + e] = hh; w3F[base + 4 + e] = (_Float16)(v - (float)hh);
    }
}

// global max of x0 ch3 -> slot; initial mask (u8) all-ones
__global__ __launch_bounds__(256) void prep_kernel(const float* __restrict__ x3,
    unsigned char* __restrict__ maskA, unsigned* __restrict__ slot)
{
    const int idx = blockIdx.x*256 + threadIdx.x;
    maskA[idx] = 1;
    float v = x3[idx];
    #pragma unroll
    for (int o=32;o;o>>=1) v = fmaxf(v, __shfl_down(v, o));
    __shared__ float red[4];
    const int lane = threadIdx.x & 63, wid = threadIdx.x >> 6;
    if (lane==0) red[wid]=v;
    __syncthreads();
    if (threadIdx.x==0){
        float m = fmaxf(fmaxf(red[0],red[1]), fmaxf(red[2],red[3]));
        atomicMax(slot, encf(m));
    }
}

// one-time transpose x0 [16][Sn] -> xT [4][Sn][4] (channel-tiled)
__global__ __launch_bounds__(256) void transpose_kernel(const float* __restrict__ x,
    float* __restrict__ xT)
{
    const int idx = blockIdx.x*256 + threadIdx.x;
    float v[16];
    #pragma unroll
    for (int c=0;c<16;++c) v[c] = x[(size_t)c*Sn + idx];
    #pragma unroll
    for (int g=0;g<4;++g){
        v4f t = {v[4*g], v[4*g+1], v[4*g+2], v[4*g+3]};
        __builtin_memcpy(xT + ((size_t)g*Sn + idx)*4, &t, 16);
    }
}

struct XBufT { v4f x[4]; float m; int v; };

__device__ __forceinline__ void prefetch_t(int t, int d, int h, int w,
    const float* __restrict__ xt, const unsigned char* __restrict__ min_, XBufT& B)
{
    const int zz = d + t/9 - 1;
    const int yy = h + (t/3)%3 - 1;
    const int xx = w + t%3 - 1;
    const int zc = clampi(zz), yc = clampi(yy), xc = clampi(xx);
    B.v = (zz==zc) & (yy==yc) & (xx==xc);
    const int noff = zc*DSTRIDE + yc*Dn + xc;
    B.m = (float)min_[noff];
    #pragma unroll
    for (int g=0;g<4;++g)
        __builtin_memcpy(&B.x[g], xt + ((size_t)g*Sn + noff)*4, 16);
}

__device__ __forceinline__ void accum_t(int t, const XBufT& A,
    const float* __restrict__ wpT, v2f* pv)
{
    const float mv = A.v ? A.m : 0.0f;
    const v2f mvv = {mv, mv};
    const float* wrow = wpT + t*48;
    #pragma unroll
    for (int i=0;i<8;++i){
        v2f xv = { A.x[i>>1][2*(i&1)], A.x[i>>1][2*(i&1)+1] };
        v2f xm = xv * mvv;                               // v_pk_mul_f32
        pv[i]    = __builtin_elementwise_fma(ld2(wrow + 2*i),      xm, pv[i]);
        pv[8+i]  = __builtin_elementwise_fma(ld2(wrow + 16 + 2*i), xm, pv[8+i]);
        pv[16+i] = __builtin_elementwise_fma(ld2(wrow + 32 + 2*i), xm, pv[16+i]);
    }
}

// fused: masked stencil dwconv (channel-tiled dwordx4, 4 instrs/tap) -> ONE
// LDS bridge (p f32, wave-private rows) -> register-chained MLP 48->64->64->16
// (weights-as-A, fused hi/lo dwordx4 loads, FULL 3-term split-f16 everywhere:
// R10 proved 2-term's ~1e-3 error flips near-threshold alive-mask voxels) ->
// c3 via same LDS rows -> tiled residual+store (+ch3 plane). ZERO barriers.
// launch_bounds (256,2): VGPR cap 256 -> NO spills (R8 lesson).
__global__ __launch_bounds__(256, 2) void update_kernel(
    const float* __restrict__ xinT, const unsigned char* __restrict__ min_,
    float* __restrict__ xout, const int final_, float* __restrict__ x3out,
    const float* __restrict__ wpT, const float* __restrict__ bpP,
    const _Float16* __restrict__ w1F, const float* __restrict__ b1,
    const _Float16* __restrict__ w2F, const float* __restrict__ b2,
    const _Float16* __restrict__ w3F, const float* __restrict__ b3,
    unsigned* __restrict__ slot_post)
{
    __shared__ __align__(16) float sP[256*PSTR];   // 53248 B

    const int tid = threadIdx.x;
    const int w = blockIdx.x*32 + (tid & 31);
    const int h = blockIdx.y*8  + (tid >> 5);
    const int d = blockIdx.z;
    const int idx = d*DSTRIDE + h*Dn + w;

    const int lane = tid & 63;
    const int wv   = tid >> 6;       // wave id 0..3
    const int lr   = lane & 15;
    const int lg   = lane >> 4;

    // ---------------- stencil dwconv (tiled dwordx4 loads) -----------------
    v2f pv[24];
    #pragma unroll
    for (int j=0;j<24;++j) pv[j] = ld2(bpP + 2*j);

    XBufT A, B;
    prefetch_t(0, d, h, w, xinT, min_, A);
    #pragma unroll 1
    for (int t=0; t<26; t+=2){
        prefetch_t(t+1, d, h, w, xinT, min_, B);
        accum_t(t, A, wpT, pv);
        prefetch_t(t+2, d, h, w, xinT, min_, A);
        accum_t(t+1, B, wpT, pv);
    }
    accum_t(26, A, wpT, pv);

    // p -> LDS row tid (f32, cols 0..47 in q*16+c order, b128 stores)
    {
        float* pr = sP + tid*PSTR;
        #pragma unroll
        for (int jj=0;jj<12;++jj){
            v4f t = {pv[2*jj].x, pv[2*jj].y, pv[2*jj+1].x, pv[2*jj+1].y};
            __builtin_memcpy(pr + 4*jj, &t, 16);
        }
    }

    // ---------------- register-chained MLP, two j-halves -------------------
    const int rowbase = 64*wv;
    #pragma unroll 1
    for (int half=0; half<2; ++half){
        const int r0 = rowbase + 32*half + lr;   // jj=0
        const int r1 = r0 + 16;                  // jj=1

        __builtin_amdgcn_s_setprio(1);
        // -------- GEMM1: c1 = W1 @ p + b1  (3-term split) ---------------
        v4f c1[4][2];
        #pragma unroll
        for (int mt=0;mt<4;++mt){
            v4f bb; __builtin_memcpy(&bb, b1 + 16*mt + 4*lg, 16);
            c1[mt][0]=bb; c1[mt][1]=bb;
        }
        #pragma unroll
        for (int ks=0;ks<3;++ks){
            v4h bh[2], bl[2];
            #pragma unroll
            for (int jj=0;jj<2;++jj){
                v4f P;
                __builtin_memcpy(&P, sP + (jj ? r1 : r0)*PSTR + 16*ks + 4*lg, 16);
                v4h hi = {(_Float16)P[0],(_Float16)P[1],(_Float16)P[2],(_Float16)P[3]};
                v4h lo = {(_Float16)(P[0]-(float)hi[0]), (_Float16)(P[1]-(float)hi[1]),
                          (_Float16)(P[2]-(float)hi[2]), (_Float16)(P[3]-(float)hi[3])};
                bh[jj]=hi; bl[jj]=lo;
            }
            #pragma unroll
            for (int mt=0;mt<4;++mt){
                v8h wv_; __builtin_memcpy(&wv_, w1F + ((mt*3+ks)*64 + lane)*8, 16);
                const v4h ah = {wv_[0],wv_[1],wv_[2],wv_[3]};
                const v4h al = {wv_[4],wv_[5],wv_[6],wv_[7]};
                #pragma unroll
                for (int jj=0;jj<2;++jj){
                    c1[mt][jj] = __builtin_amdgcn_mfma_f32_16x16x16f16(ah, bh[jj], c1[mt][jj],0,0,0);
                    c1[mt][jj] = __builtin_amdgcn_mfma_f32_16x16x16f16(al, bh[jj], c1[mt][jj],0,0,0);
                    c1[mt][jj] = __builtin_amdgcn_mfma_f32_16x16x16f16(ah, bl[jj], c1[mt][jj],0,0,0);
                }
            }
        }

        // -------- GEMM2: c2 = W2 @ tanh(c1) + b2  (3-term split) ---------
        v4f c2[4][2];
        #pragma unroll
        for (int mt=0;mt<4;++mt){
            v4f bb; __builtin_memcpy(&bb, b2 + 16*mt + 4*lg, 16);
            c2[mt][0]=bb; c2[mt][1]=bb;
        }
        #pragma unroll
        for (int ks=0;ks<4;++ks){
            v4h bh[2], bl[2];
            #pragma unroll
            for (int jj=0;jj<2;++jj){
                float t0=ftanh(c1[ks][jj][0]), t1=ftanh(c1[ks][jj][1]);
                float t2=ftanh(c1[ks][jj][2]), t3=ftanh(c1[ks][jj][3]);
                v4h hi = {(_Float16)t0,(_Float16)t1,(_Float16)t2,(_Float16)t3};
                v4h lo = {(_Float16)(t0-(float)hi[0]), (_Float16)(t1-(float)hi[1]),
                          (_Float16)(t2-(float)hi[2]), (_Float16)(t3-(float)hi[3])};
                bh[jj]=hi; bl[jj]=lo;
            }
            #pragma unroll
            for (int mt=0;mt<4;++mt){
                v8h wv_; __builtin_memcpy(&wv_, w2F + ((mt*4+ks)*64 + lane)*8, 16);
                const v4h ah = {wv_[0],wv_[1],wv_[2],wv_[3]};
                const v4h al = {wv_[4],wv_[5],wv_[6],wv_[7]};
                #pragma unroll
                for (int jj=0;jj<2;++jj){
                    c2[mt][jj] = __builtin_amdgcn_mfma_f32_16x16x16f16(ah, bh[jj], c2[mt][jj],0,0,0);
                    c2[mt][jj] = __builtin_amdgcn_mfma_f32_16x16x16f16(al, bh[jj], c2[mt][jj],0,0,0);
                    c2[mt][jj] = __builtin_amdgcn_mfma_f32_16x16x16f16(ah, bl[jj], c2[mt][jj],0,0,0);
                }
            }
        }

        // -------- GEMM3: c3 = W3 @ tanh(c2) + b3  (3-term split) ---------
        v4f c3[2];
        {
            v4f bb; __builtin_memcpy(&bb, b3 + 4*lg, 16);
            c3[0]=bb; c3[1]=bb;
        }
        #pragma unroll
        for (int ks=0;ks<4;++ks){
            v4h bh[2], bl[2];
            #pragma unroll
            for (int jj=0;jj<2;++jj){
                float t0=ftanh(c2[ks][jj][0]), t1=ftanh(c2[ks][jj][1]);
                float t2=ftanh(c2[ks][jj][2]), t3=ftanh(c2[ks][jj][3]);
                v4h hi = {(_Float16)t0,(_Float16)t1,(_Float16)t2,(_Float16)t3};
                v4h lo = {(_Float16)(t0-(float)hi[0]), (_Float16)(t1-(float)hi[1]),
                          (_Float16)(t2-(float)hi[2]), (_Float16)(t3-(float)hi[3])};
                bh[jj]=hi; bl[jj]=lo;
            }
            v8h wv_; __builtin_memcpy(&wv_, w3F + (ks*64 + lane)*8, 16);
            const v4h ah = {wv_[0],wv_[1],wv_[2],wv_[3]};
            const v4h al = {wv_[4],wv_[5],wv_[6],wv_[7]};
            #pragma unroll
            for (int jj=0;jj<2;++jj){
                c3[jj] = __builtin_amdgcn_mfma_f32_16x16x16f16(ah, bh[jj], c3[jj],0,0,0);
                c3[jj] = __builtin_amdgcn_mfma_f32_16x16x16f16(al, bh[jj], c3[jj],0,0,0);
                c3[jj] = __builtin_amdgcn_mfma_f32_16x16x16f16(ah, bl[jj], c3[jj],0,0,0);
            }
        }
        __builtin_amdgcn_s_setprio(0);

        // c3 -> LDS cols 0..15 of rows r0/r1 (wave-private; no barrier)
        __builtin_memcpy(sP + r0*PSTR + 4*lg, &c3[0], 16);
        __builtin_memcpy(sP + r1*PSTR + 4*lg, &c3[1], 16);
    }

    // ---------------- residual + tiled store (+ ch3 plane & max) -----------
    const float mcen = (float)min_[idx];
    const float* orow = sP + tid*PSTR;
    float v3 = 0.0f;
    if (!final_){
        #pragma unroll
        for (int g=0;g<4;++g){
            v4f xc; __builtin_memcpy(&xc, xinT + ((size_t)g*Sn + idx)*4, 16);
            v4f xn;
            #pragma unroll
            for (int e=0;e<4;++e) xn[e] = fmaf(xc[e], mcen, orow[4*g+e]);
            __builtin_memcpy(xout + ((size_t)g*Sn + idx)*4, &xn, 16);
            if (g==0) v3 = xn[3];
        }
        if (x3out) x3out[idx] = v3;
    } else {
        #pragma unroll
        for (int g=0;g<4;++g){
            v4f xc; __builtin_memcpy(&xc, xinT + ((size_t)g*Sn + idx)*4, 16);
            #pragma unroll
            for (int e=0;e<4;++e){
                const float xn = fmaf(xc[e], mcen, orow[4*g+e]);
                xout[(size_t)(4*g+e)*Sn + idx] = xn;
                if (g==0 && e==3) v3 = xn;
            }
        }
    }

    #pragma unroll
    for (int o=32;o;o>>=1) v3 = fmaxf(v3, __shfl_down(v3, o));
    if ((tid & 63) == 0) atomicMax(slot_post, encf(v3));
}

// alive0 from masked old ch3, alive1 from unmasked new ch3; sources are
// contiguous planes (a*_t=0) or channel-tiled (a*_t=1: ch3 at [noff*4+3]).
__global__ __launch_bounds__(256) void mask_kernel(
    const float* __restrict__ a0src, const int a0_t,
    const unsigned char* __restrict__ min_,
    const float* __restrict__ a1src, const int a1_t,
    unsigned char* __restrict__ mout,
    const unsigned* __restrict__ slot_pre, const unsigned* __restrict__ slot_post,
    unsigned* __restrict__ slot_next)
{
    const int idx = blockIdx.x*256 + threadIdx.x;
    const int w = idx % Dn;
    const int h = (idx / Dn) % Dn;
    const int d = idx / DSTRIDE;
    const float th0 = 0.1f * decf(*slot_pre);
    const float th1 = 0.1f * decf(*slot_post);
    float a0 = -INFINITY, a1 = -INFINITY;
    #pragma unroll
    for (int t=0;t<27;++t){
        const int dz=t/9-1, dy=(t/3)%3-1, dx=t%3-1;
        const int zz=d+dz, yy=h+dy, xx=w+dx;
        if ((unsigned)zz<(unsigned)Dn && (unsigned)yy<(unsigned)Dn &&
            (unsigned)xx<(unsigned)Dn){
            const int noff = idx + dz*DSTRIDE + dy*Dn + dx;
            const float x0v = a0_t ? a0src[(size_t)noff*4+3] : a0src[noff];
            const float x1v = a1_t ? a1src[(size_t)noff*4+3] : a1src[noff];
            a0 = fmaxf(a0, x0v * (float)min_[noff]);
            a1 = fmaxf(a1, x1v);
        }
    }
    const bool life = (a0 > th0) && (a1 > th1) && !(d==Dn-1 && h>=48);
    mout[idx] = life ? 1 : 0;
    const float mv = life ? 1.0f : 0.0f;

    const float xv3 = a1_t ? a1src[(size_t)idx*4+3] : a1src[idx];
    float f3 = xv3*mv;   // final ch3 value -> pre-max of next step
    #pragma unroll
    for (int o=32;o;o>>=1) f3 = fmaxf(f3, __shfl_down(f3, o));
    __shared__ float red[4];
    const int lane = threadIdx.x & 63, wid = threadIdx.x >> 6;
    if (lane==0) red[wid]=f3;
    __syncthreads();
    if (threadIdx.x==0){
        float m = fmaxf(fmaxf(red[0],red[1]), fmaxf(red[2],red[3]));
        atomicMax(slot_next, encf(m));
    }
}

// final: apply last step's mask in place on d_out (channel-major)
__global__ __launch_bounds__(256) void apply_kernel(float* __restrict__ x,
    const unsigned char* __restrict__ mk)
{
    const int idx = blockIdx.x*256 + threadIdx.x;
    const float m = (float)mk[idx];
    #pragma unroll
    for (int c=0;c<Cn;++c) x[(size_t)c*Sn+idx] *= m;
}

extern "C" void kernel_launch(void* const* d_in, const int* in_sizes, int n_in,
                              void* d_out, int out_size, void* d_ws, size_t ws_size,
                              hipStream_t stream)
{
    const float* x0 = (const float*)d_in[0];
    const float* wp = (const float*)d_in[1];
    const float* bp = (const float*)d_in[2];
    const float* w1 = (const float*)d_in[3];
    const float* b1 = (const float*)d_in[4];
    const float* w2 = (const float*)d_in[5];
    const float* b2 = (const float*)d_in[6];
    const float* w3 = (const float*)d_in[7];
    const float* b3 = (const float*)d_in[8];
    float* out = (float*)d_out;

    // ws: T0 16*Sn f32 | maskA,maskB u8 Sn each | maxv | wpT 1296 f | bpP 48 f |
    //     fused A-frag packs 16384 h | [P0,P1 ch3 planes Sn f32, if ws allows]
    float* T0 = (float*)d_ws;
    unsigned char* mA = (unsigned char*)(T0 + (size_t)Cn*Sn);
    unsigned char* mB = mA + Sn;
    unsigned* maxv = (unsigned*)(mB + Sn);
    float* wpT = (float*)(maxv + 16);
    float* bpP = wpT + 1296;
    _Float16* w1F = (_Float16*)(bpP + 48);
    _Float16* w2F = w1F + 6144;
    _Float16* w3F = w2F + 8192;
    float* Pbase = (float*)(w3F + 2048);
    const size_t need = (size_t)((char*)(Pbase + 2*(size_t)Sn) - (char*)d_ws);
    const bool planes = (ws_size >= need);
    float* P[2] = { Pbase, Pbase + Sn };
    float* T1 = out;   // d_out doubles as the second tiled state buffer

    init_kernel<<<1, 64, 0, stream>>>(maxv);
    tr_kernel<<<6, 256, 0, stream>>>(wp, bp, wpT, bpP);
    pack_kernel<<<16, 256, 0, stream>>>(w1, w2, w3, w1F, w2F, w3F);
    prep_kernel<<<Sn/256, 256, 0, stream>>>(x0 + (size_t)3*Sn, mA, &maxv[0]);
    transpose_kernel<<<Sn/256, 256, 0, stream>>>(x0, T1);

    // steps 0-2 ping-pong channel-tiled between T1(d_out) and T0(ws);
    // step 3 reads T0, writes channel-major to d_out.
    const float* xiT[4] = {T1, T0, T1, T0};
    float*       xo[4]  = {T0, T1, T0, out};
    const int    fin[4] = {0, 0, 0, 1};
    const unsigned char* mi[4] = {mA, mB, mA, mB};
    unsigned char*       mo[4] = {mB, mA, mB, mA};

    dim3 ugrid(Dn/32, Dn/8, Dn);
    for (int s=0; s<4; ++s){
        float* x3o = (planes && s<3) ? P[s&1] : nullptr;
        update_kernel<<<ugrid, 256, 0, stream>>>(xiT[s], mi[s], xo[s], fin[s], x3o,
            wpT, bpP, w1F, b1, w2F, b2, w3F, b3, &maxv[2*s+1]);

        const float* a0src; int a0t;
        if (s==0){ a0src = x0 + (size_t)3*Sn; a0t = 0; }
        else if (planes){ a0src = P[(s-1)&1]; a0t = 0; }
        else { a0src = xiT[s]; a0t = 1; }
        const float* a1src; int a1t;
        if (s==3){ a1src = out + (size_t)3*Sn; a1t = 0; }
        else if (planes){ a1src = P[s&1]; a1t = 0; }
        else { a1src = xo[s]; a1t = 1; }

        mask_kernel<<<Sn/256, 256, 0, stream>>>(a0src, a0t, mi[s], a1src, a1t,
            mo[s], &maxv[2*s], &maxv[2*s+1], &maxv[2*s+2]);
    }
    apply_kernel<<<Sn/256, 256, 0, stream>>>(out, mA);
}